// Round 8
// baseline (668.832 us; speedup 1.0000x reference)
//
#include <hip/hip_runtime.h>
#include <math.h>

#define BSZ 16
#define NPTS 2048
#define NG 128
#define GS 32
#define NBRK 38

typedef _Float16 f16;
typedef _Float16 f16x8 __attribute__((ext_vector_type(8)));
typedef float f32x4 __attribute__((ext_vector_type(4)));

// ---------- helpers ----------
__device__ __forceinline__ unsigned fkey(float x) {
    unsigned u = __float_as_uint(x);
    return (u >> 31) ? ~u : (u | 0x80000000u);
}
__device__ __forceinline__ float fkey_inv(unsigned k) {
    unsigned u = (k >> 31) ? (k ^ 0x80000000u) : ~k;
    return __uint_as_float(u);
}

// 64-lane min via DPP (no LDS/DS pipe).
__device__ __forceinline__ unsigned wave_min_u32(unsigned v) {
    unsigned t;
    t = (unsigned)__builtin_amdgcn_update_dpp(-1, (int)v, 0x111, 0xF, 0xF, false);
    v = v < t ? v : t;
    t = (unsigned)__builtin_amdgcn_update_dpp(-1, (int)v, 0x112, 0xF, 0xF, false);
    v = v < t ? v : t;
    t = (unsigned)__builtin_amdgcn_update_dpp(-1, (int)v, 0x114, 0xF, 0xF, false);
    v = v < t ? v : t;
    t = (unsigned)__builtin_amdgcn_update_dpp(-1, (int)v, 0x118, 0xF, 0xF, false);
    v = v < t ? v : t;
    t = (unsigned)__builtin_amdgcn_update_dpp(-1, (int)v, 0x142, 0xA, 0xF, false);
    v = v < t ? v : t;
    t = (unsigned)__builtin_amdgcn_update_dpp(-1, (int)v, 0x143, 0xC, 0xF, false);
    v = v < t ? v : t;
    return (unsigned)__builtin_amdgcn_readlane((int)v, 63);
}

// 64-lane max of a u64 key via DPP (old=0 is identity for unsigned max).
__device__ __forceinline__ unsigned long long wave_max_u64(unsigned long long v) {
#define DPPSTEP(ctrl, rmask)                                                                \
    {                                                                                       \
        unsigned tlo = (unsigned)__builtin_amdgcn_update_dpp(0, (int)(unsigned)v, ctrl,     \
                                                             rmask, 0xF, false);            \
        unsigned thi = (unsigned)__builtin_amdgcn_update_dpp(0, (int)(unsigned)(v >> 32),   \
                                                             ctrl, rmask, 0xF, false);      \
        unsigned long long t = ((unsigned long long)thi << 32) | tlo;                       \
        v = t > v ? t : v;                                                                  \
    }
    DPPSTEP(0x111, 0xF)
    DPPSTEP(0x112, 0xF)
    DPPSTEP(0x114, 0xF)
    DPPSTEP(0x118, 0xF)
    DPPSTEP(0x142, 0xA)
    DPPSTEP(0x143, 0xC)
#undef DPPSTEP
    unsigned rlo = (unsigned)__builtin_amdgcn_readlane((int)(unsigned)v, 63);
    unsigned rhi = (unsigned)__builtin_amdgcn_readlane((int)(unsigned)(v >> 32), 63);
    return ((unsigned long long)rhi << 32) | rlo;
}

// ---------- FPS v5 (logic unchanged; now emits packed center4 {x,y,z,|c|^2}) ----------
__global__ __launch_bounds__(256, 1) void fps_kernel_v5(const float* __restrict__ pts,
                                                        f32x4* __restrict__ center4) {
    int b = blockIdx.x;
    const float* P = pts + (size_t)b * NPTS * 3;
    int tid = threadIdx.x;
    int lane = tid & 63, wave = tid >> 6;
    __shared__ __align__(16) float Pl[NPTS * 3];
    __shared__ __align__(16) float slot[2][4][8];   // [parity][wave]{klo,khi,x,y,z,...}
#pragma unroll
    for (int i = 0; i < 6; ++i) {    // 1536 float4 = 24 KB, coalesced
        int v4 = tid + i * 256;
        ((f32x4*)Pl)[v4] = ((const f32x4*)P)[v4];
    }
    __syncthreads();
    float px[8], py[8], pz[8], mind[8];
#pragma unroll
    for (int m = 0; m < 8; ++m) {
        int j = tid + (m << 8);
        px[m] = Pl[j * 3 + 0];
        py[m] = Pl[j * 3 + 1];
        pz[m] = Pl[j * 3 + 2];
        mind[m] = 1e10f;
    }
    float cx = Pl[0], cy = Pl[1], cz = Pl[2];   // far = 0
    f32x4* C4 = center4 + (size_t)b * NG;
#pragma unroll 1
    for (int g = 0; g < NG; ++g) {
        if (tid == 0) C4[g] = (f32x4){cx, cy, cz, cx * cx + cy * cy + cz * cz};
        if (g == NG - 1) break;      // uniform: all threads exit together
        float best0 = -1.f, best1 = -1.f;
        int bm0 = 0, bm1 = 1;
#pragma unroll
        for (int m = 0; m < 8; m += 2) {   // 2 independent dep chains
            float dx0 = px[m] - cx, dy0 = py[m] - cy, dz0 = pz[m] - cz;
            float d0 = dx0 * dx0 + dy0 * dy0 + dz0 * dz0;
            float md0 = fminf(mind[m], d0);
            mind[m] = md0;
            if (md0 > best0) { best0 = md0; bm0 = m; }        // strict >: min m on tie
            float dx1 = px[m + 1] - cx, dy1 = py[m + 1] - cy, dz1 = pz[m + 1] - cz;
            float d1 = dx1 * dx1 + dy1 * dy1 + dz1 * dz1;
            float md1 = fminf(mind[m + 1], d1);
            mind[m + 1] = md1;
            if (md1 > best1) { best1 = md1; bm1 = m + 1; }
        }
        bool t = (best1 > best0) || (best1 == best0 && bm1 < bm0);
        float bv = t ? best1 : best0;
        int bi = t ? bm1 : bm0;
        unsigned j = (unsigned)(tid + (bi << 8));   // global point index
        unsigned long long key =
            ((unsigned long long)__float_as_uint(bv) << 32) | (unsigned)(~j);
        key = wave_max_u64(key);                    // broadcast to all lanes
        unsigned bj = ~(unsigned)key;
        int par = g & 1;
        if (lane < 3) slot[par][wave][2 + lane] = Pl[bj * 3 + lane];  // prefetch coords
        if (lane == 0) {
            slot[par][wave][0] = __uint_as_float((unsigned)key);
            slot[par][wave][1] = __uint_as_float((unsigned)(key >> 32));
        }
        __syncthreads();
        unsigned long long kb = 0ull;
        float nx = 0.f, ny = 0.f, nz = 0.f;
#pragma unroll
        for (int w = 0; w < 4; ++w) {
            f32x4 v = *(const f32x4*)&slot[par][w][0];   // klo,khi,x,y
            float vz = slot[par][w][4];
            unsigned long long kk =
                ((unsigned long long)__float_as_uint(v[1]) << 32) | __float_as_uint(v[0]);
            bool tw = kk > kb;
            kb = tw ? kk : kb;
            nx = tw ? v[2] : nx;
            ny = tw ? v[3] : ny;
            nz = tw ? vz : nz;
        }
        cx = nx; cy = ny; cz = nz;
    }
}

// ---------- KNN body v8: packed f32x4 db {x,y,z,|b|^2} -> 1 load + 3 FMA/pt ----------
// dv = qq + (|b|^2 - 2 q.b); same quantized key scheme as v7 (1/8192 quantum,
// idx tie-break). fp reassociation shifts dv by ~1ulp -- only flips a neighbor
// when a pair straddles a quantum edge (far below the harness tolerance; the
// chamfer rewrite precedent left absmax bit-identical).
__device__ __forceinline__ void knn_query_p4(f32x4 q, const f32x4* __restrict__ db4,
                                             int k, int* __restrict__ o, int lane) {
    const unsigned KINF = 0xFFFFFFFFu;
    float m2x = -2.f * q[0], m2y = -2.f * q[1], m2z = -2.f * q[2], qq = q[3];
    unsigned key[32];
    unsigned c0 = KINF, c1 = KINF, c2 = KINF, c3 = KINF;
#pragma unroll
    for (int m = 0; m < 32; ++m) {
        int j = lane + (m << 6);
        f32x4 b = db4[j];
        float t = fmaf(m2x, b[0], b[3]);
        t = fmaf(m2y, b[1], t);
        t = fmaf(m2z, b[2], t);
        float dv = qq + t;
        unsigned qd = (unsigned)fminf(fmaxf(dv, 0.f) * 8192.0f, 2097151.f);
        unsigned kk = (qd << 11) | (unsigned)j;
        key[m] = kk;
        if (kk < c3) {
            if (kk < c2) {
                c3 = c2;
                if (kk < c1) {
                    c2 = c1;
                    if (kk < c0) { c1 = c0; c0 = kk; } else c1 = kk;
                } else c2 = kk;
            } else c3 = kk;
        }
    }
    unsigned hw = c3;
    int ncached = 4;
    for (int r = 0; r < k; ++r) {
        bool need = (c0 == KINF) && (ncached < 32);
        if (__any(need)) {
            unsigned best = KINF;
#pragma unroll
            for (int m = 0; m < 32; ++m) {
                unsigned v = key[m];
                best = (v > hw && v < best) ? v : best;
            }
            if (need) {
                c0 = best;
                hw = best;
                ncached = (best == KINF) ? 32 : ncached + 1;
            }
        }
        unsigned g = wave_min_u32(c0);
        if (lane == 0) o[r] = (int)(g & 0x7FFu);
        if (((g & 0x7FFu) & 63u) == (unsigned)lane) {
            c0 = c1; c1 = c2; c2 = c3; c3 = KINF;
        }
    }
}

// group KNN: center4 queries vs pts4
__global__ void knn_group_kernel(const f32x4* __restrict__ center4,
                                 const f32x4* __restrict__ pts4,
                                 int* __restrict__ knnc) {
    int wave = threadIdx.x >> 6, lane = threadIdx.x & 63;
    int qidx = blockIdx.x * 4 + wave;          // BSZ*NG = 2048 exact
    int b = qidx >> 7, qi = qidx & 127;
    knn_query_p4(center4[(size_t)b * NG + qi], pts4 + (size_t)b * NPTS, GS,
                 knnc + (size_t)qidx * GS, lane);
}

// ---------- fused post-decoder KNN: 3 center-vs-pred jobs + self-KNN ----------
__global__ void knn_post_kernel(const f32x4* __restrict__ center4,
                                const f32x4* __restrict__ pred4,
                                int* __restrict__ idxa, int* __restrict__ idxb,
                                int* __restrict__ idxc, int* __restrict__ knn32) {
    int wave = threadIdx.x >> 6, lane = threadIdx.x & 63;
    if (blockIdx.x < 512) {
        int qidx = blockIdx.x * 4 + wave;        // 2048 = BSZ*128 exact
        int b = qidx >> 7, qi = qidx & 127;
        const f32x4* db4 = pred4 + (size_t)b * NPTS;
        int k; int* o;
        if (qi < 64) { k = NBRK; o = idxa + ((size_t)b * 64 + qi) * NBRK; }
        else if (qi < 96) { k = NBRK; o = idxb + ((size_t)b * 32 + qi - 64) * NBRK; }
        else { k = GS; o = idxc + ((size_t)b * 32 + qi - 96) * GS; }
        knn_query_p4(center4[(size_t)b * NG + qi], db4, k, o, lane);
    } else {
        int qidx = (blockIdx.x - 512) * 4 + wave;   // 32768 = BSZ*2048 exact
        int b = qidx >> 11, qi = qidx & 2047;
        const f32x4* db4 = pred4 + (size_t)b * NPTS;
        knn_query_p4(db4[qi], db4, GS, knn32 + (size_t)qidx * GS, lane);
    }
}

// ---------- fused gathers: pure f32x4 copies from packed sources ----------
// r0p4 (BSZ*2048) + r1p4 (BSZ*1024) from pts4 via knnc
__global__ void gather_rebuild_kernel(const f32x4* __restrict__ pts4,
                                      const int* __restrict__ knnc,
                                      f32x4* __restrict__ r0p4,
                                      f32x4* __restrict__ r1p4) {
    int t = blockIdx.x * 256 + threadIdx.x;
    if (t < BSZ * 2048) {
        int b = t >> 11, j = t & 2047;
        int s = knnc[(size_t)b * (NG * GS) + j];
        r0p4[t] = pts4[(size_t)b * NPTS + s];
    } else {
        int tt = t - BSZ * 2048;
        int b = tt >> 10, j = tt & 1023;
        int s = knnc[(size_t)b * (NG * GS) + 2048 + j];
        r1p4[tt] = pts4[(size_t)b * NPTS + s];
    }
}

// gap4 (BSZ*2432) + gbp4 (BSZ*1216) + gathc4 (BSZ*1024) from pred4
__global__ void gather_abc_kernel(const f32x4* __restrict__ pred4,
                                  const int* __restrict__ idxa,
                                  const int* __restrict__ idxb,
                                  const int* __restrict__ idxc,
                                  f32x4* __restrict__ gap4,
                                  f32x4* __restrict__ gbp4,
                                  f32x4* __restrict__ gathc4) {
    const int NA = BSZ * 2432, NB_ = BSZ * 1216, NC = BSZ * 1024;
    int t = blockIdx.x * 256 + threadIdx.x;
    if (t < NA) {
        int b = t / 2432, j = t - b * 2432;
        int s = idxa[(size_t)b * 2432 + j];
        gap4[t] = pred4[(size_t)b * NPTS + s];
    } else if (t < NA + NB_) {
        int tt = t - NA;
        int b = tt / 1216, j = tt - b * 1216;
        int s = idxb[(size_t)b * 1216 + j];
        gbp4[tt] = pred4[(size_t)b * NPTS + s];
    } else if (t < NA + NB_ + NC) {
        int tt = t - NA - NB_;
        int b = tt >> 10, j = tt & 1023;
        int s = idxc[(size_t)b * 1024 + j];
        gathc4[tt] = pred4[(size_t)b * NPTS + s];
    }
}

// ---------- fused weight cvt + pts4 pack (one dispatch) ----------
__global__ void cvt_all_kernel(const float* __restrict__ W2, const float* __restrict__ W3,
                               const float* __restrict__ W4, const float* __restrict__ pts,
                               f16* __restrict__ W2h, f16* __restrict__ W3h,
                               f16* __restrict__ W4h, f32x4* __restrict__ pts4) {
    int t = blockIdx.x * 256 + threadIdx.x;
    if (t < 32768) {                       // W2h: 256x128, ld 128, off 0
        int n = t >> 7, k = t & 127;
        W2h[t] = (f16)W2[(size_t)n * 128 + k];
    } else if (t < 163840) {               // W3h: 512x256, ld 512, off 256
        int u = t - 32768;
        int n = u >> 8, k = u & 255;
        W3h[u] = (f16)W3[(size_t)n * 512 + 256 + k];
    } else if (t < 688128) {               // W4h: 1024x512, ld 512, off 0
        int u = t - 163840;
        int n = u >> 9, k = u & 511;
        W4h[u] = (f16)W4[(size_t)n * 512 + k];
    } else if (t < 688128 + BSZ * NPTS) {  // pts4 pack
        int u = t - 688128;
        float x = pts[(size_t)u * 3 + 0], y = pts[(size_t)u * 3 + 1],
              z = pts[(size_t)u * 3 + 2];
        pts4[u] = (f32x4){x, y, z, x * x + y * y + z * z};
    }
}

// ---------- pred4 pack: {x,y,z,|p|^2} from decoder output ----------
__global__ void pack_pred4_kernel(const float* __restrict__ pred,
                                  f32x4* __restrict__ pred4) {
    int t = blockIdx.x * 256 + threadIdx.x;
    if (t >= BSZ * NPTS) return;
    float x = pred[(size_t)t * 3 + 0], y = pred[(size_t)t * 3 + 1],
          z = pred[(size_t)t * 3 + 2];
    pred4[t] = (f32x4){x, y, z, x * x + y * y + z * z};
}

// ---------- layer1: H1 = relu(bn(x @ W1^T + b1)) in fp16 (X packed f32x4) ----------
__global__ void layer1_kernel(const f32x4* __restrict__ X4, const float* __restrict__ W1,
                              const float* __restrict__ b1, const float* __restrict__ g1,
                              const float* __restrict__ be1, const float* __restrict__ m1,
                              const float* __restrict__ v1, f16* __restrict__ H1, int M) {
    __shared__ float w[384], bb[128], sg[128], sb[128], sm[128], sv[128];
    for (int i = threadIdx.x; i < 384; i += 256) w[i] = W1[i];
    if (threadIdx.x < 128) {
        int c = threadIdx.x;
        bb[c] = b1[c]; sg[c] = g1[c]; sb[c] = be1[c]; sm[c] = m1[c]; sv[c] = v1[c];
    }
    __syncthreads();
    int t = blockIdx.x * 256 + threadIdx.x;
    if (t >= M * 16) return;
    int row = t >> 4, cg = (t & 15) * 8;
    f32x4 xv = X4[row];
    float x0 = xv[0], x1 = xv[1], x2 = xv[2];
    f16x8 outv;
#pragma unroll
    for (int j = 0; j < 8; ++j) {
        int c = cg + j;
        float tv = x0 * w[c * 3] + x1 * w[c * 3 + 1] + x2 * w[c * 3 + 2] + bb[c];
        float vv = (tv - sm[c]) * rsqrtf(sv[c] + 1e-5f) * sg[c] + sb[c];
        outv[j] = (f16)fmaxf(vv, 0.f);
    }
    *(f16x8*)&H1[(size_t)row * 128 + cg] = outv;
}

// ---------- MFMA GEMM v2 (unchanged): XCD swizzle + reg prefetch ----------
__global__ __launch_bounds__(256) void mfma_gemm_kernel(
        const f16* __restrict__ A, const f16* __restrict__ W, int K, int N,
        const float* __restrict__ bias, const float* __restrict__ bias2d,
        const float* __restrict__ bng, const float* __restrict__ bnb,
        const float* __restrict__ bnm, const float* __restrict__ bnv,
        f16* __restrict__ Cout, unsigned* __restrict__ maxkey,
        int rows_per_batch, int relu) {
    __shared__ f16 Als[128 * 40];
    __shared__ f16 Bls[128 * 40];
    int tid = threadIdx.x;
    int lane = tid & 63;
    int wave = tid >> 6;
    int wm = wave & 1, wn = wave >> 1;
    int c16 = lane & 15, quad = lane >> 4;
    int gx = gridDim.x;
    int nwg = gx * gridDim.y;
    int lin = blockIdx.y * gx + blockIdx.x;
    int qc = nwg >> 3, rc = nwg & 7;
    int xcd = lin & 7, pos = lin >> 3;
    int nlin = (xcd < rc ? xcd * (qc + 1) : rc * (qc + 1) + (xcd - rc) * qc) + pos;
    int row0 = (nlin / gx) * 128, col0 = (nlin % gx) * 128;
    int sr = tid >> 2;
    int skc = (tid & 3) * 8;

    f32x4 acc[4][4];
#pragma unroll
    for (int i = 0; i < 4; ++i)
#pragma unroll
        for (int j = 0; j < 4; ++j) acc[i][j] = (f32x4){0.f, 0.f, 0.f, 0.f};

    const f16* Ab = A + (size_t)(row0 + sr) * K + skc;
    const f16* Ab2 = A + (size_t)(row0 + sr + 64) * K + skc;
    const f16* Wb = W + (size_t)(col0 + sr) * K + skc;
    const f16* Wb2 = W + (size_t)(col0 + sr + 64) * K + skc;

    f16x8 pa0 = *(const f16x8*)Ab;
    f16x8 pa1 = *(const f16x8*)Ab2;
    f16x8 pb0 = *(const f16x8*)Wb;
    f16x8 pb1 = *(const f16x8*)Wb2;

    for (int k0 = 0; k0 < K; k0 += 32) {
        *(f16x8*)&Als[sr * 40 + skc] = pa0;
        *(f16x8*)&Als[(sr + 64) * 40 + skc] = pa1;
        *(f16x8*)&Bls[sr * 40 + skc] = pb0;
        *(f16x8*)&Bls[(sr + 64) * 40 + skc] = pb1;
        __syncthreads();
        if (k0 + 32 < K) {
            int kn = k0 + 32;
            pa0 = *(const f16x8*)(Ab + kn);
            pa1 = *(const f16x8*)(Ab2 + kn);
            pb0 = *(const f16x8*)(Wb + kn);
            pb1 = *(const f16x8*)(Wb2 + kn);
        }
        f16x8 af[4], bf[4];
#pragma unroll
        for (int s = 0; s < 4; ++s) {
            af[s] = *(const f16x8*)&Als[(wm * 64 + s * 16 + c16) * 40 + quad * 8];
            bf[s] = *(const f16x8*)&Bls[(wn * 64 + s * 16 + c16) * 40 + quad * 8];
        }
#pragma unroll
        for (int ms = 0; ms < 4; ++ms)
#pragma unroll
            for (int ns = 0; ns < 4; ++ns)
                acc[ms][ns] = __builtin_amdgcn_mfma_f32_16x16x32_f16(af[ms], bf[ns],
                                                                     acc[ms][ns], 0, 0, 0);
        __syncthreads();
    }

    int b = row0 / rows_per_batch;
#pragma unroll
    for (int ns = 0; ns < 4; ++ns) {
        int col = col0 + wn * 64 + ns * 16 + c16;
        float bv = bias ? bias[col] : 0.f;
        float b2v = bias2d ? bias2d[(size_t)b * N + col] : 0.f;
        float mx = -3e38f;
#pragma unroll
        for (int ms = 0; ms < 4; ++ms) {
#pragma unroll
            for (int j = 0; j < 4; ++j) {
                float v = acc[ms][ns][j] + bv + b2v;
                if (bng) v = (v - bnm[col]) * rsqrtf(bnv[col] + 1e-5f) * bng[col] + bnb[col];
                if (relu) v = fmaxf(v, 0.f);
                if (Cout)
                    Cout[(size_t)(row0 + wm * 64 + ms * 16 + quad * 4 + j) * N + col] = (f16)v;
                mx = fmaxf(mx, v);
            }
        }
        if (maxkey) {
            mx = fmaxf(mx, __shfl_xor(mx, 16, 64));
            mx = fmaxf(mx, __shfl_xor(mx, 32, 64));
            if (quad == 0) atomicMax(&maxkey[(size_t)b * N + col], fkey(mx));
        }
    }
}

// ---------- skinny GEMM v3: wave/column, optional inline fkey decode of A ----------
__global__ void skinny_v2_kernel(const float* __restrict__ A, const float* __restrict__ W,
                                 int ldw, int woff, const float* __restrict__ bias,
                                 float* __restrict__ C, int K, int N, int relu, int akey) {
    int wave = threadIdx.x >> 6, lane = threadIdx.x & 63;
    int col = blockIdx.x * 4 + wave;
    if (col >= N) return;
    const float* w = W + (size_t)col * ldw + woff;
    float acc[16];
#pragma unroll
    for (int m = 0; m < 16; ++m) acc[m] = 0.f;
    for (int k0 = 0; k0 < K; k0 += 256) {
        f32x4 wv = *(const f32x4*)(w + k0 + lane * 4);
#pragma unroll
        for (int m = 0; m < 16; ++m) {
            f32x4 av = *(const f32x4*)(A + (size_t)m * K + k0 + lane * 4);
            if (akey) {
#pragma unroll
                for (int u = 0; u < 4; ++u) av[u] = fkey_inv(__float_as_uint(av[u]));
            }
            acc[m] += av[0] * wv[0] + av[1] * wv[1] + av[2] * wv[2] + av[3] * wv[3];
        }
    }
#pragma unroll
    for (int m = 0; m < 16; ++m)
#pragma unroll
        for (int s = 1; s < 64; s <<= 1) acc[m] += __shfl_xor(acc[m], s, 64);
    if (lane == 0) {
        float bv = bias[col];
#pragma unroll
        for (int m = 0; m < 16; ++m) {
            float v = acc[m] + bv;
            if (relu) v = fmaxf(v, 0.f);
            C[(size_t)m * N + col] = v;
        }
    }
}

// ---------- chamfer v3 (unchanged): thread-per-A-point, B in LDS broadcast ----------
__global__ __launch_bounds__(256) void chamfer4_kernel(const f32x4* __restrict__ r0p4,
                                                       const f32x4* __restrict__ gap4,
                                                       const f32x4* __restrict__ r1p4,
                                                       const f32x4* __restrict__ gbp4,
                                                       float* __restrict__ accum) {
    __shared__ __align__(16) float Bl[2432 * 4];   // 38.9 KB max
    int blk = blockIdx.x;
    const f32x4 *A4, *B4; int na, nb, base, bpb; float* slot;
    if (blk < 128)      { A4 = r0p4; na = 2048; B4 = gap4; nb = 2432; slot = accum + 0; base = 0;   bpb = 8; }
    else if (blk < 288) { A4 = gap4; na = 2432; B4 = r0p4; nb = 2048; slot = accum + 1; base = 128; bpb = 10; }
    else if (blk < 352) { A4 = r1p4; na = 1024; B4 = gbp4; nb = 1216; slot = accum + 2; base = 288; bpb = 4; }
    else                { A4 = gbp4; na = 1216; B4 = r1p4; nb = 1024; slot = accum + 3; base = 352; bpb = 5; }
    int rel = blk - base;
    int b = rel / bpb, chunk = rel - b * bpb;
    for (int i = threadIdx.x; i < nb; i += 256)
        ((f32x4*)Bl)[i] = B4[(size_t)b * nb + i];
    __syncthreads();
    int aidx = chunk * 256 + threadIdx.x;
    float val = 0.f;
    if (aidx < na) {
        f32x4 a = A4[(size_t)b * na + aidx];
        float m2x = -2.f * a[0], m2y = -2.f * a[1], m2z = -2.f * a[2];
        float m0 = 3e38f, m1 = 3e38f, m2 = 3e38f, m3 = 3e38f;   // 4 indep chains
        for (int j = 0; j < nb; j += 4) {                       // nb % 4 == 0 always
            f32x4 b0 = ((const f32x4*)Bl)[j + 0];
            f32x4 b1 = ((const f32x4*)Bl)[j + 1];
            f32x4 b2 = ((const f32x4*)Bl)[j + 2];
            f32x4 b3 = ((const f32x4*)Bl)[j + 3];
            float t0 = fmaf(m2z, b0[2], fmaf(m2y, b0[1], fmaf(m2x, b0[0], b0[3])));
            float t1 = fmaf(m2z, b1[2], fmaf(m2y, b1[1], fmaf(m2x, b1[0], b1[3])));
            float t2 = fmaf(m2z, b2[2], fmaf(m2y, b2[1], fmaf(m2x, b2[0], b2[3])));
            float t3 = fmaf(m2z, b3[2], fmaf(m2y, b3[1], fmaf(m2x, b3[0], b3[3])));
            m0 = fminf(m0, t0); m1 = fminf(m1, t1);
            m2 = fminf(m2, t2); m3 = fminf(m3, t3);
        }
        float m = fminf(fminf(m0, m1), fminf(m2, m3));
        val = sqrtf(fmaxf(a[3] + m, 1e-12f));
    }
    __shared__ float sdata[256];
    sdata[threadIdx.x] = val;
    __syncthreads();
    for (int s = 128; s > 0; s >>= 1) {
        if (threadIdx.x < s) sdata[threadIdx.x] += sdata[threadIdx.x + s];
        __syncthreads();
    }
    if (threadIdx.x == 0) atomicAdd(slot, sdata[0]);
}

// ---------- 3x3 symmetric smallest eigenvector (double, analytic) ----------
__device__ void smallest_evec(double cxx, double cxy, double cxz,
                              double cyy, double cyz, double czz, double ev[3]) {
    double p1 = cxy * cxy + cxz * cxz + cyz * cyz;
    double q = (cxx + cyy + czz) / 3.0;
    double p2 = (cxx - q) * (cxx - q) + (cyy - q) * (cyy - q) + (czz - q) * (czz - q) + 2.0 * p1;
    double lam = q;
    if (p2 > 0.0) {
        double p = sqrt(p2 / 6.0);
        double b00 = (cxx - q) / p, b11 = (cyy - q) / p, b22 = (czz - q) / p;
        double b01 = cxy / p, b02 = cxz / p, b12 = cyz / p;
        double detB = b00 * (b11 * b22 - b12 * b12) - b01 * (b01 * b22 - b12 * b02)
                    + b02 * (b01 * b12 - b11 * b02);
        double r = detB * 0.5;
        r = r < -1.0 ? -1.0 : (r > 1.0 ? 1.0 : r);
        double phi = acos(r) / 3.0;
        lam = q + 2.0 * p * cos(phi + 2.0943951023931953);
    }
    double r0x = cxx - lam, r0y = cxy, r0z = cxz;
    double r1x = cxy, r1y = cyy - lam, r1z = cyz;
    double r2x = cxz, r2y = cyz, r2z = czz - lam;
    double c0x = r0y * r1z - r0z * r1y, c0y = r0z * r1x - r0x * r1z, c0z = r0x * r1y - r0y * r1x;
    double c1x = r0y * r2z - r0z * r2y, c1y = r0z * r2x - r0x * r2z, c1z = r0x * r2y - r0y * r2x;
    double c2x = r1y * r2z - r1z * r2y, c2y = r1z * r2x - r1x * r2z, c2z = r1x * r2y - r1y * r2x;
    double n0 = c0x * c0x + c0y * c0y + c0z * c0z;
    double n1 = c1x * c1x + c1y * c1y + c1z * c1z;
    double n2 = c2x * c2x + c2y * c2y + c2z * c2z;
    double bx = c0x, by = c0y, bz = c0z, bn = n0;
    if (n1 > bn) { bx = c1x; by = c1y; bz = c1z; bn = n1; }
    if (n2 > bn) { bx = c2x; by = c2y; bz = c2z; bn = n2; }
    if (bn < 1e-280) { ev[0] = 1.0; ev[1] = 0.0; ev[2] = 0.0; return; }
    double inv = 1.0 / sqrt(bn);
    ev[0] = bx * inv; ev[1] = by * inv; ev[2] = bz * inv;
}

// ---------- normals v3: single-pass moments from packed pred4 ----------
__global__ __launch_bounds__(64) void normals_kernel(const f32x4* __restrict__ pred4,
                                                     const int* __restrict__ knn,
                                                     float* __restrict__ nrm) {
    int t = blockIdx.x * 64 + threadIdx.x;
    if (t >= BSZ * NPTS) return;
    int b = t / NPTS, i = t % NPTS;
    const f32x4* P4 = pred4 + (size_t)b * NPTS;
    const int* id = knn + (size_t)t * 32;
    double sx = 0, sy = 0, sz = 0;
    double sxx = 0, sxy = 0, sxz = 0, syy = 0, syz = 0, szz = 0;
#pragma unroll
    for (int k0 = 0; k0 < 32; k0 += 4) {
        int4 jj = *(const int4*)&id[k0];
#pragma unroll
        for (int u = 0; u < 4; ++u) {
            int j = (u == 0) ? jj.x : (u == 1) ? jj.y : (u == 2) ? jj.z : jj.w;
            f32x4 p = P4[j];
            double x = (double)p[0], y = (double)p[1], z = (double)p[2];
            sx += x; sy += y; sz += z;
            sxx += x * x; sxy += x * y; sxz += x * z;
            syy += y * y; syz += y * z; szz += z * z;
        }
    }
    double mx = sx * (1.0 / 32.0), my = sy * (1.0 / 32.0), mz = sz * (1.0 / 32.0);
    double cxx = sxx * (1.0 / 32.0) - mx * mx;
    double cxy = sxy * (1.0 / 32.0) - mx * my;
    double cxz = sxz * (1.0 / 32.0) - mx * mz;
    double cyy = syy * (1.0 / 32.0) - my * my;
    double cyz = syz * (1.0 / 32.0) - my * mz;
    double czz = szz * (1.0 / 32.0) - mz * mz;
    double ev[3];
    smallest_evec(cxx, cxy, cxz, cyy, cyz, czz, ev);
    f32x4 q = P4[i];
    double proj = (sx - 32.0 * (double)q[0]) * ev[0] + (sy - 32.0 * (double)q[1]) * ev[1]
                + (sz - 32.0 * (double)q[2]) * ev[2];
    double s = (proj >= 0.0) ? 1.0 : -1.0;
    nrm[(size_t)t * 3 + 0] = (float)(ev[0] * s);
    nrm[(size_t)t * 3 + 1] = (float)(ev[1] * s);
    nrm[(size_t)t * 3 + 2] = (float)(ev[2] * s);
}

// ---------- fused loss tail: manifold (blocks 0..127) + latent (blocks 128..191) ----------
__global__ void loss_tail_kernel(const float* __restrict__ nrm,
                                 const int* __restrict__ knn32,
                                 const unsigned* __restrict__ k1,
                                 const unsigned* __restrict__ k2,
                                 float* __restrict__ accum) {
    float val = 0.f;
    float* slot;
    if (blockIdx.x < 128) {
        slot = accum + 5;
        int t = blockIdx.x * 256 + threadIdx.x;      // BSZ*2048 = 32768 exact
        int b = t >> 11;
        const float* NB = nrm + (size_t)b * NPTS * 3;
        const int* id = knn32 + (size_t)t * 32;
        int j0 = id[0];
        float ax = NB[j0 * 3 + 0], ay = NB[j0 * 3 + 1], az = NB[j0 * 3 + 2];
        float an = fmaxf(sqrtf(ax * ax + ay * ay + az * az), 1e-6f);
        float x[8]; float s = 0.f;
        for (int k = 0; k < 8; ++k) {
            int j = id[k];
            float bx = NB[j * 3 + 0], by = NB[j * 3 + 1], bz = NB[j * 3 + 2];
            float bn_ = fmaxf(sqrtf(bx * bx + by * by + bz * bz), 1e-6f);
            float c = (ax * bx + ay * by + az * bz) / (an * bn_);
            x[k] = 1.f - c; s += x[k];
        }
        float mean = s / 8.f;
        float var = 0.f;
        for (int k = 0; k < 8; ++k) { float d = x[k] - mean; var += d * d; }
        val = sqrtf(var / 7.f);
    } else {
        slot = accum + 4;
        int t = (blockIdx.x - 128) * 256 + threadIdx.x;   // BSZ*1024 = 16384 exact
        float d = fkey_inv(k1[t]) - fkey_inv(k2[t]);
        float ad = fabsf(d);
        val = (ad < 1.f) ? (0.5f * d * d) : (ad - 0.5f);
    }
    __shared__ float sdata[256];
    sdata[threadIdx.x] = val;
    __syncthreads();
    for (int s2 = 128; s2 > 0; s2 >>= 1) {
        if (threadIdx.x < s2) sdata[threadIdx.x] += sdata[threadIdx.x + s2];
        __syncthreads();
    }
    if (threadIdx.x == 0) atomicAdd(slot, sdata[0]);
}

__global__ void finalize_kernel(const float* __restrict__ acc, float* __restrict__ out) {
    float l_recon = 0.5f * (acc[0] / (16.f * 2048.f) + acc[1] / (16.f * 2432.f));
    float l_match = 0.5f * (acc[2] / (16.f * 1024.f) + acc[3] / (16.f * 1216.f));
    float l_latent = acc[4] / (16.f * 1024.f);
    float l_man = 0.1f * (acc[5] / (16.f * 2048.f));
    out[0] = l_recon + l_match + l_latent + l_man;
    out[1] = l_recon;
    out[2] = l_match;
    out[3] = l_latent;
    out[4] = l_man;
}

// ================= host =================
extern "C" void kernel_launch(void* const* d_in, const int* in_sizes, int n_in,
                              void* d_out, int out_size, void* d_ws, size_t ws_size,
                              hipStream_t stream) {
    (void)in_sizes; (void)n_in; (void)out_size; (void)ws_size;
    const float* pts = (const float*)d_in[0];
    const float* W1 = (const float*)d_in[1];
    const float* b1 = (const float*)d_in[2];
    const float* g1 = (const float*)d_in[3];
    const float* be1 = (const float*)d_in[4];
    const float* m1 = (const float*)d_in[5];
    const float* v1 = (const float*)d_in[6];
    const float* W2 = (const float*)d_in[7];
    const float* b2 = (const float*)d_in[8];
    const float* W3 = (const float*)d_in[9];
    const float* b3 = (const float*)d_in[10];
    const float* g2 = (const float*)d_in[11];
    const float* be2 = (const float*)d_in[12];
    const float* m2 = (const float*)d_in[13];
    const float* v2 = (const float*)d_in[14];
    const float* W4 = (const float*)d_in[15];
    const float* b4 = (const float*)d_in[16];
    const float* D1W = (const float*)d_in[17];
    const float* D1b = (const float*)d_in[18];
    const float* D2W = (const float*)d_in[19];
    const float* D2b = (const float*)d_in[20];
    const float* D3W = (const float*)d_in[21];
    const float* D3b = (const float*)d_in[22];
    const float* D4W = (const float*)d_in[23];
    const float* D4b = (const float*)d_in[24];

    char* ws = (char*)d_ws;
    size_t off = 0;
    auto alloc = [&](size_t bytes) -> void* {
        void* p = ws + off;
        off += (bytes + 255) & ~(size_t)255;
        return p;
    };
    f32x4* center4  = (f32x4*)alloc((size_t)BSZ * NG * 16);
    f32x4* pts4     = (f32x4*)alloc((size_t)BSZ * NPTS * 16);
    f32x4* pred4    = (f32x4*)alloc((size_t)BSZ * NPTS * 16);
    int*   knnc     = (int*)  alloc((size_t)BSZ * NG * GS * 4);
    f32x4* r0p4     = (f32x4*)alloc((size_t)BSZ * 2048 * 16);
    f32x4* r1p4     = (f32x4*)alloc((size_t)BSZ * 1024 * 16);
    f16*   W2h      = (f16*)  alloc((size_t)256 * 128 * 2);
    f16*   W3h      = (f16*)  alloc((size_t)512 * 256 * 2);
    f16*   W4h      = (f16*)  alloc((size_t)1024 * 512 * 2);
    f16*   H1h      = (f16*)  alloc((size_t)BSZ * 2048 * 128 * 2);
    f16*   H2h      = (f16*)  alloc((size_t)BSZ * 2048 * 256 * 2);
    f16*   H3h      = (f16*)  alloc((size_t)BSZ * 2048 * 512 * 2);
    // contiguous key region + accum: ONE memset covers all
    unsigned* keybase = (unsigned*)alloc(((size_t)BSZ * 2560 + 64) * 4);
    unsigned* gmaxkey1 = keybase;
    unsigned* gmaxkey2 = keybase + (size_t)BSZ * 256;
    unsigned* featkey1 = keybase + (size_t)BSZ * 512;
    unsigned* featkey2 = keybase + (size_t)BSZ * 512 + (size_t)BSZ * 1024;
    float* accum = (float*)(keybase + (size_t)BSZ * 2560);
    float* gpart    = (float*)alloc((size_t)BSZ * 512 * 4);
    float* dh1      = (float*)alloc((size_t)BSZ * 2048 * 4);
    float* dh2      = (float*)alloc((size_t)BSZ * 2048 * 4);
    float* dh3      = (float*)alloc((size_t)BSZ * 2048 * 4);
    float* pred     = (float*)alloc((size_t)BSZ * 6144 * 4);
    int*   idxa     = (int*)  alloc((size_t)BSZ * 64 * NBRK * 4);
    int*   idxb     = (int*)  alloc((size_t)BSZ * 32 * NBRK * 4);
    int*   idxc     = (int*)  alloc((size_t)BSZ * 32 * 32 * 4);
    f32x4* gap4     = (f32x4*)alloc((size_t)BSZ * 2432 * 16);
    f32x4* gbp4     = (f32x4*)alloc((size_t)BSZ * 1216 * 16);
    f32x4* gathc4   = (f32x4*)alloc((size_t)BSZ * 1024 * 16);
    int*   knn32    = (int*)  alloc((size_t)BSZ * 2048 * 32 * 4);
    float* nrmbuf   = (float*)alloc((size_t)BSZ * 2048 * 3 * 4);

    // ONE memset: all atomicMax key buffers + accum slots
    hipMemsetAsync(keybase, 0, ((size_t)BSZ * 2560 + 8) * 4, stream);

    cvt_all_kernel<<<2816, 256, 0, stream>>>(W2, W3, W4, pts, W2h, W3h, W4h, pts4);

    // FPS + grouping
    fps_kernel_v5<<<BSZ, 256, 0, stream>>>(pts, center4);
    knn_group_kernel<<<(BSZ * NG) / 4, 256, 0, stream>>>(center4, pts4, knnc);
    gather_rebuild_kernel<<<(BSZ * 3072) / 256, 256, 0, stream>>>(pts4, knnc, r0p4, r1p4);

    // encoder: 5 dispatches
    auto enc = [&](const f32x4* X4, int n, unsigned* gkey, unsigned* fkeyout) {
        int M = BSZ * n;
        layer1_kernel<<<M / 16, 256, 0, stream>>>(X4, W1, b1, g1, be1, m1, v1, H1h, M);
        mfma_gemm_kernel<<<dim3(256 / 128, M / 128), 256, 0, stream>>>(
            H1h, W2h, 128, 256, b2, nullptr, nullptr, nullptr, nullptr, nullptr,
            H2h, gkey, n, 0);
        skinny_v2_kernel<<<(512 + 3) / 4, 256, 0, stream>>>(
            (const float*)gkey, W3, 512, 0, b3, gpart, 256, 512, 0, 1);
        mfma_gemm_kernel<<<dim3(512 / 128, M / 128), 256, 0, stream>>>(
            H2h, W3h, 256, 512, nullptr, gpart, g2, be2, m2, v2, H3h, nullptr, n, 1);
        mfma_gemm_kernel<<<dim3(1024 / 128, M / 128), 256, 0, stream>>>(
            H3h, W4h, 512, 1024, b4, nullptr, nullptr, nullptr, nullptr, nullptr,
            nullptr, fkeyout, n, 0);
    };

    enc(r0p4, 2048, gmaxkey1, featkey1);

    // decoder (skinny M=16, fp32; D1 decodes featkey1 inline)
    skinny_v2_kernel<<<2048 / 4, 256, 0, stream>>>((const float*)featkey1, D1W, 1024, 0,
                                                   D1b, dh1, 1024, 2048, 1, 1);
    skinny_v2_kernel<<<2048 / 4, 256, 0, stream>>>(dh1, D2W, 2048, 0, D2b, dh2,
                                                   2048, 2048, 1, 0);
    skinny_v2_kernel<<<2048 / 4, 256, 0, stream>>>(dh2, D3W, 2048, 0, D3b, dh3,
                                                   2048, 2048, 1, 0);
    skinny_v2_kernel<<<6144 / 4, 256, 0, stream>>>(dh3, D4W, 2048, 0, D4b, pred,
                                                   2048, 6144, 0, 0);
    pack_pred4_kernel<<<(BSZ * NPTS) / 256, 256, 0, stream>>>(pred, pred4);

    // all pred-database KNNs in one dispatch
    knn_post_kernel<<<512 + (BSZ * NPTS) / 4, 256, 0, stream>>>(center4, pred4, idxa,
                                                                idxb, idxc, knn32);
    gather_abc_kernel<<<(BSZ * 4672) / 256, 256, 0, stream>>>(pred4, idxa, idxb, idxc,
                                                              gap4, gbp4, gathc4);
    chamfer4_kernel<<<432, 256, 0, stream>>>(r0p4, gap4, r1p4, gbp4, accum);
    normals_kernel<<<(BSZ * NPTS) / 64, 64, 0, stream>>>(pred4, knn32, nrmbuf);

    enc(gathc4, 1024, gmaxkey2, featkey2);
    loss_tail_kernel<<<192, 256, 0, stream>>>(nrmbuf, knn32, featkey1, featkey2, accum);

    finalize_kernel<<<1, 1, 0, stream>>>(accum, (float*)d_out);
}

// Round 10
// 663.525 us; speedup vs baseline: 1.0080x; 1.0080x over previous
//
#include <hip/hip_runtime.h>
#include <math.h>

#define BSZ 16
#define NPTS 2048
#define NG 128
#define GS 32
#define NBRK 38

typedef _Float16 f16;
typedef _Float16 f16x8 __attribute__((ext_vector_type(8)));
typedef float f32x4 __attribute__((ext_vector_type(4)));

// ---------- helpers ----------
__device__ __forceinline__ unsigned fkey(float x) {
    unsigned u = __float_as_uint(x);
    return (u >> 31) ? ~u : (u | 0x80000000u);
}
__device__ __forceinline__ float fkey_inv(unsigned k) {
    unsigned u = (k >> 31) ? (k ^ 0x80000000u) : ~k;
    return __uint_as_float(u);
}

// 64-lane min via DPP (no LDS/DS pipe).
__device__ __forceinline__ unsigned wave_min_u32(unsigned v) {
    unsigned t;
    t = (unsigned)__builtin_amdgcn_update_dpp(-1, (int)v, 0x111, 0xF, 0xF, false);
    v = v < t ? v : t;
    t = (unsigned)__builtin_amdgcn_update_dpp(-1, (int)v, 0x112, 0xF, 0xF, false);
    v = v < t ? v : t;
    t = (unsigned)__builtin_amdgcn_update_dpp(-1, (int)v, 0x114, 0xF, 0xF, false);
    v = v < t ? v : t;
    t = (unsigned)__builtin_amdgcn_update_dpp(-1, (int)v, 0x118, 0xF, 0xF, false);
    v = v < t ? v : t;
    t = (unsigned)__builtin_amdgcn_update_dpp(-1, (int)v, 0x142, 0xA, 0xF, false);
    v = v < t ? v : t;
    t = (unsigned)__builtin_amdgcn_update_dpp(-1, (int)v, 0x143, 0xC, 0xF, false);
    v = v < t ? v : t;
    return (unsigned)__builtin_amdgcn_readlane((int)v, 63);
}

// 64-lane max of a u64 key via DPP (old=0 is identity for unsigned max).
__device__ __forceinline__ unsigned long long wave_max_u64(unsigned long long v) {
#define DPPSTEP(ctrl, rmask)                                                                \
    {                                                                                       \
        unsigned tlo = (unsigned)__builtin_amdgcn_update_dpp(0, (int)(unsigned)v, ctrl,     \
                                                             rmask, 0xF, false);            \
        unsigned thi = (unsigned)__builtin_amdgcn_update_dpp(0, (int)(unsigned)(v >> 32),   \
                                                             ctrl, rmask, 0xF, false);      \
        unsigned long long t = ((unsigned long long)thi << 32) | tlo;                       \
        v = t > v ? t : v;                                                                  \
    }
    DPPSTEP(0x111, 0xF)
    DPPSTEP(0x112, 0xF)
    DPPSTEP(0x114, 0xF)
    DPPSTEP(0x118, 0xF)
    DPPSTEP(0x142, 0xA)
    DPPSTEP(0x143, 0xC)
#undef DPPSTEP
    unsigned rlo = (unsigned)__builtin_amdgcn_readlane((int)(unsigned)v, 63);
    unsigned rhi = (unsigned)__builtin_amdgcn_readlane((int)(unsigned)(v >> 32), 63);
    return ((unsigned long long)rhi << 32) | rlo;
}

// ---------- FPS v5 (unchanged): 4 waves, one barrier/iter, packed center4 out ----------
__global__ __launch_bounds__(256, 1) void fps_kernel_v5(const float* __restrict__ pts,
                                                        f32x4* __restrict__ center4) {
    int b = blockIdx.x;
    const float* P = pts + (size_t)b * NPTS * 3;
    int tid = threadIdx.x;
    int lane = tid & 63, wave = tid >> 6;
    __shared__ __align__(16) float Pl[NPTS * 3];
    __shared__ __align__(16) float slot[2][4][8];   // [parity][wave]{klo,khi,x,y,z,...}
#pragma unroll
    for (int i = 0; i < 6; ++i) {    // 1536 float4 = 24 KB, coalesced
        int v4 = tid + i * 256;
        ((f32x4*)Pl)[v4] = ((const f32x4*)P)[v4];
    }
    __syncthreads();
    float px[8], py[8], pz[8], mind[8];
#pragma unroll
    for (int m = 0; m < 8; ++m) {
        int j = tid + (m << 8);
        px[m] = Pl[j * 3 + 0];
        py[m] = Pl[j * 3 + 1];
        pz[m] = Pl[j * 3 + 2];
        mind[m] = 1e10f;
    }
    float cx = Pl[0], cy = Pl[1], cz = Pl[2];   // far = 0
    f32x4* C4 = center4 + (size_t)b * NG;
#pragma unroll 1
    for (int g = 0; g < NG; ++g) {
        if (tid == 0) C4[g] = (f32x4){cx, cy, cz, cx * cx + cy * cy + cz * cz};
        if (g == NG - 1) break;      // uniform: all threads exit together
        float best0 = -1.f, best1 = -1.f;
        int bm0 = 0, bm1 = 1;
#pragma unroll
        for (int m = 0; m < 8; m += 2) {   // 2 independent dep chains
            float dx0 = px[m] - cx, dy0 = py[m] - cy, dz0 = pz[m] - cz;
            float d0 = dx0 * dx0 + dy0 * dy0 + dz0 * dz0;
            float md0 = fminf(mind[m], d0);
            mind[m] = md0;
            if (md0 > best0) { best0 = md0; bm0 = m; }        // strict >: min m on tie
            float dx1 = px[m + 1] - cx, dy1 = py[m + 1] - cy, dz1 = pz[m + 1] - cz;
            float d1 = dx1 * dx1 + dy1 * dy1 + dz1 * dz1;
            float md1 = fminf(mind[m + 1], d1);
            mind[m + 1] = md1;
            if (md1 > best1) { best1 = md1; bm1 = m + 1; }
        }
        bool t = (best1 > best0) || (best1 == best0 && bm1 < bm0);
        float bv = t ? best1 : best0;
        int bi = t ? bm1 : bm0;
        unsigned j = (unsigned)(tid + (bi << 8));   // global point index
        unsigned long long key =
            ((unsigned long long)__float_as_uint(bv) << 32) | (unsigned)(~j);
        key = wave_max_u64(key);                    // broadcast to all lanes
        unsigned bj = ~(unsigned)key;
        int par = g & 1;
        if (lane < 3) slot[par][wave][2 + lane] = Pl[bj * 3 + lane];  // prefetch coords
        if (lane == 0) {
            slot[par][wave][0] = __uint_as_float((unsigned)key);
            slot[par][wave][1] = __uint_as_float((unsigned)(key >> 32));
        }
        __syncthreads();
        unsigned long long kb = 0ull;
        float nx = 0.f, ny = 0.f, nz = 0.f;
#pragma unroll
        for (int w = 0; w < 4; ++w) {
            f32x4 v = *(const f32x4*)&slot[par][w][0];   // klo,khi,x,y
            float vz = slot[par][w][4];
            unsigned long long kk =
                ((unsigned long long)__float_as_uint(v[1]) << 32) | __float_as_uint(v[0]);
            bool tw = kk > kb;
            kb = tw ? kk : kb;
            nx = tw ? v[2] : nx;
            ny = tw ? v[3] : ny;
            nz = tw ? vz : nz;
        }
        cx = nx; cy = ny; cz = nz;
    }
}

// ---------- KNN core v9: returns per-lane winner (lane r holds r-th NN index) ----------
// Same math/keys as v8 (packed db, 1 load + 3 FMA/pt, quantized key + idx tiebreak).
// Instead of lane0 storing o[r] each round, lane r keeps round-r's winner in a
// register -- callers either store indices coalesced or gather points directly.
__device__ __forceinline__ int knn_query_core(f32x4 q, const f32x4* __restrict__ db4,
                                              int k, int lane) {
    const unsigned KINF = 0xFFFFFFFFu;
    float m2x = -2.f * q[0], m2y = -2.f * q[1], m2z = -2.f * q[2], qq = q[3];
    unsigned key[32];
    unsigned c0 = KINF, c1 = KINF, c2 = KINF, c3 = KINF;
#pragma unroll
    for (int m = 0; m < 32; ++m) {
        int j = lane + (m << 6);
        f32x4 b = db4[j];
        float t = fmaf(m2x, b[0], b[3]);
        t = fmaf(m2y, b[1], t);
        t = fmaf(m2z, b[2], t);
        float dv = qq + t;
        unsigned qd = (unsigned)fminf(fmaxf(dv, 0.f) * 8192.0f, 2097151.f);
        unsigned kk = (qd << 11) | (unsigned)j;
        key[m] = kk;
        if (kk < c3) {
            if (kk < c2) {
                c3 = c2;
                if (kk < c1) {
                    c2 = c1;
                    if (kk < c0) { c1 = c0; c0 = kk; } else c1 = kk;
                } else c2 = kk;
            } else c3 = kk;
        }
    }
    unsigned hw = c3;
    int ncached = 4;
    int mywin = 0;
    for (int r = 0; r < k; ++r) {
        bool need = (c0 == KINF) && (ncached < 32);
        if (__any(need)) {
            unsigned best = KINF;
#pragma unroll
            for (int m = 0; m < 32; ++m) {
                unsigned v = key[m];
                best = (v > hw && v < best) ? v : best;
            }
            if (need) {
                c0 = best;
                hw = best;
                ncached = (best == KINF) ? 32 : ncached + 1;
            }
        }
        unsigned g = wave_min_u32(c0);
        int idx = (int)(g & 0x7FFu);
        if (lane == r) mywin = idx;
        if (((unsigned)idx & 63u) == (unsigned)lane) {   // owner pops its c0 (== g)
            c0 = c1; c1 = c2; c2 = c3; c3 = KINF;
        }
    }
    return mywin;
}

// ---------- group KNN + direct gather: centers 0..95 vs pts4 -> r0p4/r1p4 ----------
// knnc eliminated (was only read by the old gather); groups 96..127 never gathered.
__global__ void knn_group_gather_kernel(const f32x4* __restrict__ center4,
                                        const f32x4* __restrict__ pts4,
                                        f32x4* __restrict__ r0p4,
                                        f32x4* __restrict__ r1p4) {
    int wave = threadIdx.x >> 6, lane = threadIdx.x & 63;
    int qidx = blockIdx.x * 4 + wave;          // [0, BSZ*96)
    int b = qidx / 96, qi = qidx - b * 96;
    const f32x4* db4 = pts4 + (size_t)b * NPTS;
    int win = knn_query_core(center4[(size_t)b * NG + qi], db4, GS, lane);
    if (lane < GS) {
        f32x4 p = db4[win];
        if (qi < 64) r0p4[(size_t)b * 2048 + qi * GS + lane] = p;
        else         r1p4[(size_t)b * 1024 + (qi - 64) * GS + lane] = p;
    }
}

// ---------- post-decoder KNN + direct gather (idxa/b/c eliminated) + self-KNN ----------
__global__ void knn_post_kernel(const f32x4* __restrict__ center4,
                                const f32x4* __restrict__ pred4,
                                f32x4* __restrict__ gap4, f32x4* __restrict__ gbp4,
                                f32x4* __restrict__ gathc4, int* __restrict__ knn32) {
    int wave = threadIdx.x >> 6, lane = threadIdx.x & 63;
    if (blockIdx.x < 512) {
        int qidx = blockIdx.x * 4 + wave;        // 2048 = BSZ*128 exact
        int b = qidx >> 7, qi = qidx & 127;
        const f32x4* db4 = pred4 + (size_t)b * NPTS;
        int k = (qi < 96) ? NBRK : GS;           // wave-uniform
        int win = knn_query_core(center4[(size_t)b * NG + qi], db4, k, lane);
        if (lane < k) {
            f32x4 p = db4[win];
            if (qi < 64)      gap4[(size_t)b * 2432 + qi * NBRK + lane] = p;
            else if (qi < 96) gbp4[(size_t)b * 1216 + (qi - 64) * NBRK + lane] = p;
            else              gathc4[(size_t)b * 1024 + (qi - 96) * GS + lane] = p;
        }
    } else {
        int qidx = (blockIdx.x - 512) * 4 + wave;   // 32768 = BSZ*2048 exact
        int b = qidx >> 11, qi = qidx & 2047;
        const f32x4* db4 = pred4 + (size_t)b * NPTS;
        int win = knn_query_core(db4[qi], db4, GS, lane);
        if (lane < GS) knn32[(size_t)qidx * GS + lane] = win;
    }
}

// ---------- fused weight cvt + pts4 pack + key/accum zero-init (one dispatch) ----------
__global__ void cvt_all_kernel(const float* __restrict__ W2, const float* __restrict__ W3,
                               const float* __restrict__ W4, const float* __restrict__ pts,
                               f16* __restrict__ W2h, f16* __restrict__ W3h,
                               f16* __restrict__ W4h, f32x4* __restrict__ pts4,
                               unsigned* __restrict__ keybase, int zero_words) {
    int t = blockIdx.x * 256 + threadIdx.x;
    if (t < 32768) {                       // W2h: 256x128, ld 128, off 0
        int n = t >> 7, k = t & 127;
        W2h[t] = (f16)W2[(size_t)n * 128 + k];
    } else if (t < 163840) {               // W3h: 512x256, ld 512, off 256
        int u = t - 32768;
        int n = u >> 8, k = u & 255;
        W3h[u] = (f16)W3[(size_t)n * 512 + 256 + k];
    } else if (t < 688128) {               // W4h: 1024x512, ld 512, off 0
        int u = t - 163840;
        int n = u >> 9, k = u & 511;
        W4h[u] = (f16)W4[(size_t)n * 512 + k];
    } else if (t < 720896) {               // pts4 pack (BSZ*NPTS = 32768)
        int u = t - 688128;
        float x = pts[(size_t)u * 3 + 0], y = pts[(size_t)u * 3 + 1],
              z = pts[(size_t)u * 3 + 2];
        pts4[u] = (f32x4){x, y, z, x * x + y * y + z * z};
    } else if (t < 720896 + zero_words) {  // zero atomic key buffers + accum + ticket
        keybase[t - 720896] = 0u;
    }
}

// ---------- layer1: H1 = relu(bn(x @ W1^T + b1)) in fp16 (X packed f32x4) ----------
__global__ void layer1_kernel(const f32x4* __restrict__ X4, const float* __restrict__ W1,
                              const float* __restrict__ b1, const float* __restrict__ g1,
                              const float* __restrict__ be1, const float* __restrict__ m1,
                              const float* __restrict__ v1, f16* __restrict__ H1, int M) {
    __shared__ float w[384], bb[128], sg[128], sb[128], sm[128], sv[128];
    for (int i = threadIdx.x; i < 384; i += 256) w[i] = W1[i];
    if (threadIdx.x < 128) {
        int c = threadIdx.x;
        bb[c] = b1[c]; sg[c] = g1[c]; sb[c] = be1[c]; sm[c] = m1[c]; sv[c] = v1[c];
    }
    __syncthreads();
    int t = blockIdx.x * 256 + threadIdx.x;
    if (t >= M * 16) return;
    int row = t >> 4, cg = (t & 15) * 8;
    f32x4 xv = X4[row];
    float x0 = xv[0], x1 = xv[1], x2 = xv[2];
    f16x8 outv;
#pragma unroll
    for (int j = 0; j < 8; ++j) {
        int c = cg + j;
        float tv = x0 * w[c * 3] + x1 * w[c * 3 + 1] + x2 * w[c * 3 + 2] + bb[c];
        float vv = (tv - sm[c]) * rsqrtf(sv[c] + 1e-5f) * sg[c] + sb[c];
        outv[j] = (f16)fmaxf(vv, 0.f);
    }
    *(f16x8*)&H1[(size_t)row * 128 + cg] = outv;
}

// ---------- MFMA GEMM v2 (unchanged): XCD swizzle + reg prefetch ----------
__global__ __launch_bounds__(256) void mfma_gemm_kernel(
        const f16* __restrict__ A, const f16* __restrict__ W, int K, int N,
        const float* __restrict__ bias, const float* __restrict__ bias2d,
        const float* __restrict__ bng, const float* __restrict__ bnb,
        const float* __restrict__ bnm, const float* __restrict__ bnv,
        f16* __restrict__ Cout, unsigned* __restrict__ maxkey,
        int rows_per_batch, int relu) {
    __shared__ f16 Als[128 * 40];
    __shared__ f16 Bls[128 * 40];
    int tid = threadIdx.x;
    int lane = tid & 63;
    int wave = tid >> 6;
    int wm = wave & 1, wn = wave >> 1;
    int c16 = lane & 15, quad = lane >> 4;
    int gx = gridDim.x;
    int nwg = gx * gridDim.y;
    int lin = blockIdx.y * gx + blockIdx.x;
    int qc = nwg >> 3, rc = nwg & 7;
    int xcd = lin & 7, pos = lin >> 3;
    int nlin = (xcd < rc ? xcd * (qc + 1) : rc * (qc + 1) + (xcd - rc) * qc) + pos;
    int row0 = (nlin / gx) * 128, col0 = (nlin % gx) * 128;
    int sr = tid >> 2;
    int skc = (tid & 3) * 8;

    f32x4 acc[4][4];
#pragma unroll
    for (int i = 0; i < 4; ++i)
#pragma unroll
        for (int j = 0; j < 4; ++j) acc[i][j] = (f32x4){0.f, 0.f, 0.f, 0.f};

    const f16* Ab = A + (size_t)(row0 + sr) * K + skc;
    const f16* Ab2 = A + (size_t)(row0 + sr + 64) * K + skc;
    const f16* Wb = W + (size_t)(col0 + sr) * K + skc;
    const f16* Wb2 = W + (size_t)(col0 + sr + 64) * K + skc;

    f16x8 pa0 = *(const f16x8*)Ab;
    f16x8 pa1 = *(const f16x8*)Ab2;
    f16x8 pb0 = *(const f16x8*)Wb;
    f16x8 pb1 = *(const f16x8*)Wb2;

    for (int k0 = 0; k0 < K; k0 += 32) {
        *(f16x8*)&Als[sr * 40 + skc] = pa0;
        *(f16x8*)&Als[(sr + 64) * 40 + skc] = pa1;
        *(f16x8*)&Bls[sr * 40 + skc] = pb0;
        *(f16x8*)&Bls[(sr + 64) * 40 + skc] = pb1;
        __syncthreads();
        if (k0 + 32 < K) {
            int kn = k0 + 32;
            pa0 = *(const f16x8*)(Ab + kn);
            pa1 = *(const f16x8*)(Ab2 + kn);
            pb0 = *(const f16x8*)(Wb + kn);
            pb1 = *(const f16x8*)(Wb2 + kn);
        }
        f16x8 af[4], bf[4];
#pragma unroll
        for (int s = 0; s < 4; ++s) {
            af[s] = *(const f16x8*)&Als[(wm * 64 + s * 16 + c16) * 40 + quad * 8];
            bf[s] = *(const f16x8*)&Bls[(wn * 64 + s * 16 + c16) * 40 + quad * 8];
        }
#pragma unroll
        for (int ms = 0; ms < 4; ++ms)
#pragma unroll
            for (int ns = 0; ns < 4; ++ns)
                acc[ms][ns] = __builtin_amdgcn_mfma_f32_16x16x32_f16(af[ms], bf[ns],
                                                                     acc[ms][ns], 0, 0, 0);
        __syncthreads();
    }

    int b = row0 / rows_per_batch;
#pragma unroll
    for (int ns = 0; ns < 4; ++ns) {
        int col = col0 + wn * 64 + ns * 16 + c16;
        float bv = bias ? bias[col] : 0.f;
        float b2v = bias2d ? bias2d[(size_t)b * N + col] : 0.f;
        float mx = -3e38f;
#pragma unroll
        for (int ms = 0; ms < 4; ++ms) {
#pragma unroll
            for (int j = 0; j < 4; ++j) {
                float v = acc[ms][ns][j] + bv + b2v;
                if (bng) v = (v - bnm[col]) * rsqrtf(bnv[col] + 1e-5f) * bng[col] + bnb[col];
                if (relu) v = fmaxf(v, 0.f);
                if (Cout)
                    Cout[(size_t)(row0 + wm * 64 + ms * 16 + quad * 4 + j) * N + col] = (f16)v;
                mx = fmaxf(mx, v);
            }
        }
        if (maxkey) {
            mx = fmaxf(mx, __shfl_xor(mx, 16, 64));
            mx = fmaxf(mx, __shfl_xor(mx, 32, 64));
            if (quad == 0) atomicMax(&maxkey[(size_t)b * N + col], fkey(mx));
        }
    }
}

// ---------- skinny GEMM v3: wave/column, optional inline fkey decode of A ----------
__global__ void skinny_v2_kernel(const float* __restrict__ A, const float* __restrict__ W,
                                 int ldw, int woff, const float* __restrict__ bias,
                                 float* __restrict__ C, int K, int N, int relu, int akey) {
    int wave = threadIdx.x >> 6, lane = threadIdx.x & 63;
    int col = blockIdx.x * 4 + wave;
    if (col >= N) return;
    const float* w = W + (size_t)col * ldw + woff;
    float acc[16];
#pragma unroll
    for (int m = 0; m < 16; ++m) acc[m] = 0.f;
    for (int k0 = 0; k0 < K; k0 += 256) {
        f32x4 wv = *(const f32x4*)(w + k0 + lane * 4);
#pragma unroll
        for (int m = 0; m < 16; ++m) {
            f32x4 av = *(const f32x4*)(A + (size_t)m * K + k0 + lane * 4);
            if (akey) {
#pragma unroll
                for (int u = 0; u < 4; ++u) av[u] = fkey_inv(__float_as_uint(av[u]));
            }
            acc[m] += av[0] * wv[0] + av[1] * wv[1] + av[2] * wv[2] + av[3] * wv[3];
        }
    }
#pragma unroll
    for (int m = 0; m < 16; ++m)
#pragma unroll
        for (int s = 1; s < 64; s <<= 1) acc[m] += __shfl_xor(acc[m], s, 64);
    if (lane == 0) {
        float bv = bias[col];
#pragma unroll
        for (int m = 0; m < 16; ++m) {
            float v = acc[m] + bv;
            if (relu) v = fmaxf(v, 0.f);
            C[(size_t)m * N + col] = v;
        }
    }
}

// ---------- D4 skinny variant: 3 columns (one point) per wave -> packed pred4 ----------
// Absorbs pack_pred4: wave computes x,y,z dots for its point across all 16 batch
// rows, writes pred4[b*2048+p] = {x,y,z,|p|^2} directly. pred (x3) buffer gone.
__global__ void skinny_pred3_kernel(const float* __restrict__ A,
                                    const float* __restrict__ W,
                                    const float* __restrict__ bias,
                                    f32x4* __restrict__ pred4) {
    int wave = threadIdx.x >> 6, lane = threadIdx.x & 63;
    int p = blockIdx.x * 4 + wave;           // [0, 2048)
    const float* w0 = W + (size_t)(3 * p + 0) * 2048;
    const float* w1 = W + (size_t)(3 * p + 1) * 2048;
    const float* w2 = W + (size_t)(3 * p + 2) * 2048;
    float ax[16], ay[16], az[16];
#pragma unroll
    for (int m = 0; m < 16; ++m) { ax[m] = 0.f; ay[m] = 0.f; az[m] = 0.f; }
    for (int k0 = 0; k0 < 2048; k0 += 256) {
        f32x4 wx = *(const f32x4*)(w0 + k0 + lane * 4);
        f32x4 wy = *(const f32x4*)(w1 + k0 + lane * 4);
        f32x4 wz = *(const f32x4*)(w2 + k0 + lane * 4);
#pragma unroll
        for (int m = 0; m < 16; ++m) {
            f32x4 av = *(const f32x4*)(A + (size_t)m * 2048 + k0 + lane * 4);
            ax[m] += av[0] * wx[0] + av[1] * wx[1] + av[2] * wx[2] + av[3] * wx[3];
            ay[m] += av[0] * wy[0] + av[1] * wy[1] + av[2] * wy[2] + av[3] * wy[3];
            az[m] += av[0] * wz[0] + av[1] * wz[1] + av[2] * wz[2] + av[3] * wz[3];
        }
    }
#pragma unroll
    for (int m = 0; m < 16; ++m)
#pragma unroll
        for (int s = 1; s < 64; s <<= 1) {
            ax[m] += __shfl_xor(ax[m], s, 64);
            ay[m] += __shfl_xor(ay[m], s, 64);
            az[m] += __shfl_xor(az[m], s, 64);
        }
    if (lane == 0) {
        float bx = bias[3 * p + 0], by = bias[3 * p + 1], bz = bias[3 * p + 2];
#pragma unroll
        for (int m = 0; m < 16; ++m) {
            float x = ax[m] + bx, y = ay[m] + by, z = az[m] + bz;
            pred4[(size_t)m * 2048 + p] = (f32x4){x, y, z, x * x + y * y + z * z};
        }
    }
}

// ---------- chamfer v3 (unchanged): thread-per-A-point, B in LDS broadcast ----------
__global__ __launch_bounds__(256) void chamfer4_kernel(const f32x4* __restrict__ r0p4,
                                                       const f32x4* __restrict__ gap4,
                                                       const f32x4* __restrict__ r1p4,
                                                       const f32x4* __restrict__ gbp4,
                                                       float* __restrict__ accum) {
    __shared__ __align__(16) float Bl[2432 * 4];   // 38.9 KB max
    int blk = blockIdx.x;
    const f32x4 *A4, *B4; int na, nb, base, bpb; float* slot;
    if (blk < 128)      { A4 = r0p4; na = 2048; B4 = gap4; nb = 2432; slot = accum + 0; base = 0;   bpb = 8; }
    else if (blk < 288) { A4 = gap4; na = 2432; B4 = r0p4; nb = 2048; slot = accum + 1; base = 128; bpb = 10; }
    else if (blk < 352) { A4 = r1p4; na = 1024; B4 = gbp4; nb = 1216; slot = accum + 2; base = 288; bpb = 4; }
    else                { A4 = gbp4; na = 1216; B4 = r1p4; nb = 1024; slot = accum + 3; base = 352; bpb = 5; }
    int rel = blk - base;
    int b = rel / bpb, chunk = rel - b * bpb;
    for (int i = threadIdx.x; i < nb; i += 256)
        ((f32x4*)Bl)[i] = B4[(size_t)b * nb + i];
    __syncthreads();
    int aidx = chunk * 256 + threadIdx.x;
    float val = 0.f;
    if (aidx < na) {
        f32x4 a = A4[(size_t)b * na + aidx];
        float m2x = -2.f * a[0], m2y = -2.f * a[1], m2z = -2.f * a[2];
        float m0 = 3e38f, m1 = 3e38f, m2 = 3e38f, m3 = 3e38f;   // 4 indep chains
        for (int j = 0; j < nb; j += 4) {                       // nb % 4 == 0 always
            f32x4 b0 = ((const f32x4*)Bl)[j + 0];
            f32x4 b1 = ((const f32x4*)Bl)[j + 1];
            f32x4 b2 = ((const f32x4*)Bl)[j + 2];
            f32x4 b3 = ((const f32x4*)Bl)[j + 3];
            float t0 = fmaf(m2z, b0[2], fmaf(m2y, b0[1], fmaf(m2x, b0[0], b0[3])));
            float t1 = fmaf(m2z, b1[2], fmaf(m2y, b1[1], fmaf(m2x, b1[0], b1[3])));
            float t2 = fmaf(m2z, b2[2], fmaf(m2y, b2[1], fmaf(m2x, b2[0], b2[3])));
            float t3 = fmaf(m2z, b3[2], fmaf(m2y, b3[1], fmaf(m2x, b3[0], b3[3])));
            m0 = fminf(m0, t0); m1 = fminf(m1, t1);
            m2 = fminf(m2, t2); m3 = fminf(m3, t3);
        }
        float m = fminf(fminf(m0, m1), fminf(m2, m3));
        val = sqrtf(fmaxf(a[3] + m, 1e-12f));
    }
    __shared__ float sdata[256];
    sdata[threadIdx.x] = val;
    __syncthreads();
    for (int s = 128; s > 0; s >>= 1) {
        if (threadIdx.x < s) sdata[threadIdx.x] += sdata[threadIdx.x + s];
        __syncthreads();
    }
    if (threadIdx.x == 0) atomicAdd(slot, sdata[0]);
}

// ---------- 3x3 symmetric smallest eigenvector (double, analytic) ----------
__device__ void smallest_evec(double cxx, double cxy, double cxz,
                              double cyy, double cyz, double czz, double ev[3]) {
    double p1 = cxy * cxy + cxz * cxz + cyz * cyz;
    double q = (cxx + cyy + czz) / 3.0;
    double p2 = (cxx - q) * (cxx - q) + (cyy - q) * (cyy - q) + (czz - q) * (czz - q) + 2.0 * p1;
    double lam = q;
    if (p2 > 0.0) {
        double p = sqrt(p2 / 6.0);
        double b00 = (cxx - q) / p, b11 = (cyy - q) / p, b22 = (czz - q) / p;
        double b01 = cxy / p, b02 = cxz / p, b12 = cyz / p;
        double detB = b00 * (b11 * b22 - b12 * b12) - b01 * (b01 * b22 - b12 * b02)
                    + b02 * (b01 * b12 - b11 * b02);
        double r = detB * 0.5;
        r = r < -1.0 ? -1.0 : (r > 1.0 ? 1.0 : r);
        double phi = acos(r) / 3.0;
        lam = q + 2.0 * p * cos(phi + 2.0943951023931953);
    }
    double r0x = cxx - lam, r0y = cxy, r0z = cxz;
    double r1x = cxy, r1y = cyy - lam, r1z = cyz;
    double r2x = cxz, r2y = cyz, r2z = czz - lam;
    double c0x = r0y * r1z - r0z * r1y, c0y = r0z * r1x - r0x * r1z, c0z = r0x * r1y - r0y * r1x;
    double c1x = r0y * r2z - r0z * r2y, c1y = r0z * r2x - r0x * r2z, c1z = r0x * r2y - r0y * r2x;
    double c2x = r1y * r2z - r1z * r2y, c2y = r1z * r2x - r1x * r2z, c2z = r1x * r2y - r1y * r2x;
    double n0 = c0x * c0x + c0y * c0y + c0z * c0z;
    double n1 = c1x * c1x + c1y * c1y + c1z * c1z;
    double n2 = c2x * c2x + c2y * c2y + c2z * c2z;
    double bx = c0x, by = c0y, bz = c0z, bn = n0;
    if (n1 > bn) { bx = c1x; by = c1y; bz = c1z; bn = n1; }
    if (n2 > bn) { bx = c2x; by = c2y; bz = c2z; bn = n2; }
    if (bn < 1e-280) { ev[0] = 1.0; ev[1] = 0.0; ev[2] = 0.0; return; }
    double inv = 1.0 / sqrt(bn);
    ev[0] = bx * inv; ev[1] = by * inv; ev[2] = bz * inv;
}

// ---------- normals v3 (unchanged): single-pass moments from packed pred4 ----------
__global__ __launch_bounds__(64) void normals_kernel(const f32x4* __restrict__ pred4,
                                                     const int* __restrict__ knn,
                                                     float* __restrict__ nrm) {
    int t = blockIdx.x * 64 + threadIdx.x;
    if (t >= BSZ * NPTS) return;
    int b = t / NPTS, i = t % NPTS;
    const f32x4* P4 = pred4 + (size_t)b * NPTS;
    const int* id = knn + (size_t)t * 32;
    double sx = 0, sy = 0, sz = 0;
    double sxx = 0, sxy = 0, sxz = 0, syy = 0, syz = 0, szz = 0;
#pragma unroll
    for (int k0 = 0; k0 < 32; k0 += 4) {
        int4 jj = *(const int4*)&id[k0];
#pragma unroll
        for (int u = 0; u < 4; ++u) {
            int j = (u == 0) ? jj.x : (u == 1) ? jj.y : (u == 2) ? jj.z : jj.w;
            f32x4 p = P4[j];
            double x = (double)p[0], y = (double)p[1], z = (double)p[2];
            sx += x; sy += y; sz += z;
            sxx += x * x; sxy += x * y; sxz += x * z;
            syy += y * y; syz += y * z; szz += z * z;
        }
    }
    double mx = sx * (1.0 / 32.0), my = sy * (1.0 / 32.0), mz = sz * (1.0 / 32.0);
    double cxx = sxx * (1.0 / 32.0) - mx * mx;
    double cxy = sxy * (1.0 / 32.0) - mx * my;
    double cxz = sxz * (1.0 / 32.0) - mx * mz;
    double cyy = syy * (1.0 / 32.0) - my * my;
    double cyz = syz * (1.0 / 32.0) - my * mz;
    double czz = szz * (1.0 / 32.0) - mz * mz;
    double ev[3];
    smallest_evec(cxx, cxy, cxz, cyy, cyz, czz, ev);
    f32x4 q = P4[i];
    double proj = (sx - 32.0 * (double)q[0]) * ev[0] + (sy - 32.0 * (double)q[1]) * ev[1]
                + (sz - 32.0 * (double)q[2]) * ev[2];
    double s = (proj >= 0.0) ? 1.0 : -1.0;
    nrm[(size_t)t * 3 + 0] = (float)(ev[0] * s);
    nrm[(size_t)t * 3 + 1] = (float)(ev[1] * s);
    nrm[(size_t)t * 3 + 2] = (float)(ev[2] * s);
}

// ---------- fused loss tail + finalize (completion-ticket) ----------
// blocks 0..127: manifold; 128..191: latent. After the slot atomicAdd each block
// threadfences then increments a device-scope ticket; the LAST block (191 prior
// arrivals) reads all 6 slots via device-scope RMW loads and writes d_out.
// chamfer4 slots [0..3] are from an earlier stream-ordered kernel -> visible.
__global__ void loss_tail_kernel(const float* __restrict__ nrm,
                                 const int* __restrict__ knn32,
                                 const unsigned* __restrict__ k1,
                                 const unsigned* __restrict__ k2,
                                 float* __restrict__ accum,
                                 float* __restrict__ out) {
    float val = 0.f;
    float* slot;
    if (blockIdx.x < 128) {
        slot = accum + 5;
        int t = blockIdx.x * 256 + threadIdx.x;      // BSZ*2048 = 32768 exact
        int b = t >> 11;
        const float* NB = nrm + (size_t)b * NPTS * 3;
        const int* id = knn32 + (size_t)t * 32;
        int j0 = id[0];
        float ax = NB[j0 * 3 + 0], ay = NB[j0 * 3 + 1], az = NB[j0 * 3 + 2];
        float an = fmaxf(sqrtf(ax * ax + ay * ay + az * az), 1e-6f);
        float x[8]; float s = 0.f;
        for (int k = 0; k < 8; ++k) {
            int j = id[k];
            float bx = NB[j * 3 + 0], by = NB[j * 3 + 1], bz = NB[j * 3 + 2];
            float bn_ = fmaxf(sqrtf(bx * bx + by * by + bz * bz), 1e-6f);
            float c = (ax * bx + ay * by + az * bz) / (an * bn_);
            x[k] = 1.f - c; s += x[k];
        }
        float mean = s / 8.f;
        float var = 0.f;
        for (int k = 0; k < 8; ++k) { float d = x[k] - mean; var += d * d; }
        val = sqrtf(var / 7.f);
    } else {
        slot = accum + 4;
        int t = (blockIdx.x - 128) * 256 + threadIdx.x;   // BSZ*1024 = 16384 exact
        float d = fkey_inv(k1[t]) - fkey_inv(k2[t]);
        float ad = fabsf(d);
        val = (ad < 1.f) ? (0.5f * d * d) : (ad - 0.5f);
    }
    __shared__ float sdata[256];
    sdata[threadIdx.x] = val;
    __syncthreads();
    for (int s2 = 128; s2 > 0; s2 >>= 1) {
        if (threadIdx.x < s2) sdata[threadIdx.x] += sdata[threadIdx.x + s2];
        __syncthreads();
    }
    if (threadIdx.x == 0) {
        atomicAdd(slot, sdata[0]);
        __threadfence();
        unsigned tk = atomicAdd((unsigned*)(accum + 6), 1u);
        if (tk == 191u) {                 // last block: all adds visible
            float a0 = atomicAdd(&accum[0], 0.f);
            float a1 = atomicAdd(&accum[1], 0.f);
            float a2 = atomicAdd(&accum[2], 0.f);
            float a3 = atomicAdd(&accum[3], 0.f);
            float a4 = atomicAdd(&accum[4], 0.f);
            float a5 = atomicAdd(&accum[5], 0.f);
            float l_recon = 0.5f * (a0 / (16.f * 2048.f) + a1 / (16.f * 2432.f));
            float l_match = 0.5f * (a2 / (16.f * 1024.f) + a3 / (16.f * 1216.f));
            float l_latent = a4 / (16.f * 1024.f);
            float l_man = 0.1f * (a5 / (16.f * 2048.f));
            out[0] = l_recon + l_match + l_latent + l_man;
            out[1] = l_recon;
            out[2] = l_match;
            out[3] = l_latent;
            out[4] = l_man;
        }
    }
}

// ================= host =================
extern "C" void kernel_launch(void* const* d_in, const int* in_sizes, int n_in,
                              void* d_out, int out_size, void* d_ws, size_t ws_size,
                              hipStream_t stream) {
    (void)in_sizes; (void)n_in; (void)out_size; (void)ws_size;
    const float* pts = (const float*)d_in[0];
    const float* W1 = (const float*)d_in[1];
    const float* b1 = (const float*)d_in[2];
    const float* g1 = (const float*)d_in[3];
    const float* be1 = (const float*)d_in[4];
    const float* m1 = (const float*)d_in[5];
    const float* v1 = (const float*)d_in[6];
    const float* W2 = (const float*)d_in[7];
    const float* b2 = (const float*)d_in[8];
    const float* W3 = (const float*)d_in[9];
    const float* b3 = (const float*)d_in[10];
    const float* g2 = (const float*)d_in[11];
    const float* be2 = (const float*)d_in[12];
    const float* m2 = (const float*)d_in[13];
    const float* v2 = (const float*)d_in[14];
    const float* W4 = (const float*)d_in[15];
    const float* b4 = (const float*)d_in[16];
    const float* D1W = (const float*)d_in[17];
    const float* D1b = (const float*)d_in[18];
    const float* D2W = (const float*)d_in[19];
    const float* D2b = (const float*)d_in[20];
    const float* D3W = (const float*)d_in[21];
    const float* D3b = (const float*)d_in[22];
    const float* D4W = (const float*)d_in[23];
    const float* D4b = (const float*)d_in[24];

    char* ws = (char*)d_ws;
    size_t off = 0;
    auto alloc = [&](size_t bytes) -> void* {
        void* p = ws + off;
        off += (bytes + 255) & ~(size_t)255;
        return p;
    };
    f32x4* center4  = (f32x4*)alloc((size_t)BSZ * NG * 16);
    f32x4* pts4     = (f32x4*)alloc((size_t)BSZ * NPTS * 16);
    f32x4* pred4    = (f32x4*)alloc((size_t)BSZ * NPTS * 16);
    f32x4* r0p4     = (f32x4*)alloc((size_t)BSZ * 2048 * 16);
    f32x4* r1p4     = (f32x4*)alloc((size_t)BSZ * 1024 * 16);
    f16*   W2h      = (f16*)  alloc((size_t)256 * 128 * 2);
    f16*   W3h      = (f16*)  alloc((size_t)512 * 256 * 2);
    f16*   W4h      = (f16*)  alloc((size_t)1024 * 512 * 2);
    f16*   H1h      = (f16*)  alloc((size_t)BSZ * 2048 * 128 * 2);
    f16*   H2h      = (f16*)  alloc((size_t)BSZ * 2048 * 256 * 2);
    f16*   H3h      = (f16*)  alloc((size_t)BSZ * 2048 * 512 * 2);
    // contiguous key region + accum + ticket: zero-inited by cvt_all
    const int kZeroWords = BSZ * 2560 + 16;
    unsigned* keybase = (unsigned*)alloc(((size_t)BSZ * 2560 + 64) * 4);
    unsigned* gmaxkey1 = keybase;
    unsigned* gmaxkey2 = keybase + (size_t)BSZ * 256;
    unsigned* featkey1 = keybase + (size_t)BSZ * 512;
    unsigned* featkey2 = keybase + (size_t)BSZ * 512 + (size_t)BSZ * 1024;
    float* accum = (float*)(keybase + (size_t)BSZ * 2560);
    float* gpart    = (float*)alloc((size_t)BSZ * 512 * 4);
    float* dh1      = (float*)alloc((size_t)BSZ * 2048 * 4);
    float* dh2      = (float*)alloc((size_t)BSZ * 2048 * 4);
    float* dh3      = (float*)alloc((size_t)BSZ * 2048 * 4);
    f32x4* gap4     = (f32x4*)alloc((size_t)BSZ * 2432 * 16);
    f32x4* gbp4     = (f32x4*)alloc((size_t)BSZ * 1216 * 16);
    f32x4* gathc4   = (f32x4*)alloc((size_t)BSZ * 1024 * 16);
    int*   knn32    = (int*)  alloc((size_t)BSZ * 2048 * 32 * 4);
    float* nrmbuf   = (float*)alloc((size_t)BSZ * 2048 * 3 * 4);

    // 1: weights cvt + pts4 pack + zero keys/accum/ticket (memset dispatch absorbed)
    cvt_all_kernel<<<(720896 + kZeroWords + 255) / 256, 256, 0, stream>>>(
        W2, W3, W4, pts, W2h, W3h, W4h, pts4, keybase, kZeroWords);

    // 2: FPS   3: group-KNN + direct gather (knnc + gather dispatch absorbed)
    fps_kernel_v5<<<BSZ, 256, 0, stream>>>(pts, center4);
    knn_group_gather_kernel<<<(BSZ * 96) / 4, 256, 0, stream>>>(center4, pts4,
                                                                r0p4, r1p4);

    // encoder: 5 dispatches
    auto enc = [&](const f32x4* X4, int n, unsigned* gkey, unsigned* fkeyout) {
        int M = BSZ * n;
        layer1_kernel<<<M / 16, 256, 0, stream>>>(X4, W1, b1, g1, be1, m1, v1, H1h, M);
        mfma_gemm_kernel<<<dim3(256 / 128, M / 128), 256, 0, stream>>>(
            H1h, W2h, 128, 256, b2, nullptr, nullptr, nullptr, nullptr, nullptr,
            H2h, gkey, n, 0);
        skinny_v2_kernel<<<(512 + 3) / 4, 256, 0, stream>>>(
            (const float*)gkey, W3, 512, 0, b3, gpart, 256, 512, 0, 1);
        mfma_gemm_kernel<<<dim3(512 / 128, M / 128), 256, 0, stream>>>(
            H2h, W3h, 256, 512, nullptr, gpart, g2, be2, m2, v2, H3h, nullptr, n, 1);
        mfma_gemm_kernel<<<dim3(1024 / 128, M / 128), 256, 0, stream>>>(
            H3h, W4h, 512, 1024, b4, nullptr, nullptr, nullptr, nullptr, nullptr,
            nullptr, fkeyout, n, 0);
    };

    // 4-8: enc1
    enc(r0p4, 2048, gmaxkey1, featkey1);

    // 9-12: decoder; D4 variant writes packed pred4 (pack dispatch absorbed)
    skinny_v2_kernel<<<2048 / 4, 256, 0, stream>>>((const float*)featkey1, D1W, 1024, 0,
                                                   D1b, dh1, 1024, 2048, 1, 1);
    skinny_v2_kernel<<<2048 / 4, 256, 0, stream>>>(dh1, D2W, 2048, 0, D2b, dh2,
                                                   2048, 2048, 1, 0);
    skinny_v2_kernel<<<2048 / 4, 256, 0, stream>>>(dh2, D3W, 2048, 0, D3b, dh3,
                                                   2048, 2048, 1, 0);
    skinny_pred3_kernel<<<2048 / 4, 256, 0, stream>>>(dh3, D4W, D4b, pred4);

    // 13: all pred-database KNNs + direct gathers (gather_abc dispatch absorbed)
    knn_post_kernel<<<512 + (BSZ * NPTS) / 4, 256, 0, stream>>>(center4, pred4, gap4,
                                                                gbp4, gathc4, knn32);
    // 14-15
    chamfer4_kernel<<<432, 256, 0, stream>>>(r0p4, gap4, r1p4, gbp4, accum);
    normals_kernel<<<(BSZ * NPTS) / 64, 64, 0, stream>>>(pred4, knn32, nrmbuf);

    // 16-20: enc2
    enc(gathc4, 1024, gmaxkey2, featkey2);

    // 21: loss tail + fused finalize (ticket)
    loss_tail_kernel<<<192, 256, 0, stream>>>(nrmbuf, knn32, featkey1, featkey2,
                                              accum, (float*)d_out);
}

// Round 13
// 660.305 us; speedup vs baseline: 1.0129x; 1.0049x over previous
//
#include <hip/hip_runtime.h>
#include <math.h>

#define BSZ 16
#define NPTS 2048
#define NG 128
#define GS 32
#define NBRK 38

typedef _Float16 f16;
typedef _Float16 f16x8 __attribute__((ext_vector_type(8)));
typedef float f32x4 __attribute__((ext_vector_type(4)));

// ---------- helpers ----------
__device__ __forceinline__ unsigned fkey(float x) {
    unsigned u = __float_as_uint(x);
    return (u >> 31) ? ~u : (u | 0x80000000u);
}
__device__ __forceinline__ float fkey_inv(unsigned k) {
    unsigned u = (k >> 31) ? (k ^ 0x80000000u) : ~k;
    return __uint_as_float(u);
}

// 64-lane min via DPP (no LDS/DS pipe).
__device__ __forceinline__ unsigned wave_min_u32(unsigned v) {
    unsigned t;
    t = (unsigned)__builtin_amdgcn_update_dpp(-1, (int)v, 0x111, 0xF, 0xF, false);
    v = v < t ? v : t;
    t = (unsigned)__builtin_amdgcn_update_dpp(-1, (int)v, 0x112, 0xF, 0xF, false);
    v = v < t ? v : t;
    t = (unsigned)__builtin_amdgcn_update_dpp(-1, (int)v, 0x114, 0xF, 0xF, false);
    v = v < t ? v : t;
    t = (unsigned)__builtin_amdgcn_update_dpp(-1, (int)v, 0x118, 0xF, 0xF, false);
    v = v < t ? v : t;
    t = (unsigned)__builtin_amdgcn_update_dpp(-1, (int)v, 0x142, 0xA, 0xF, false);
    v = v < t ? v : t;
    t = (unsigned)__builtin_amdgcn_update_dpp(-1, (int)v, 0x143, 0xC, 0xF, false);
    v = v < t ? v : t;
    return (unsigned)__builtin_amdgcn_readlane((int)v, 63);
}

// 64-lane max of a u64 key via DPP (old=0 is identity for unsigned max).
__device__ __forceinline__ unsigned long long wave_max_u64(unsigned long long v) {
#define DPPSTEP(ctrl, rmask)                                                                \
    {                                                                                       \
        unsigned tlo = (unsigned)__builtin_amdgcn_update_dpp(0, (int)(unsigned)v, ctrl,     \
                                                             rmask, 0xF, false);            \
        unsigned thi = (unsigned)__builtin_amdgcn_update_dpp(0, (int)(unsigned)(v >> 32),   \
                                                             ctrl, rmask, 0xF, false);      \
        unsigned long long t = ((unsigned long long)thi << 32) | tlo;                       \
        v = t > v ? t : v;                                                                  \
    }
    DPPSTEP(0x111, 0xF)
    DPPSTEP(0x112, 0xF)
    DPPSTEP(0x114, 0xF)
    DPPSTEP(0x118, 0xF)
    DPPSTEP(0x142, 0xA)
    DPPSTEP(0x143, 0xC)
#undef DPPSTEP
    unsigned rlo = (unsigned)__builtin_amdgcn_readlane((int)(unsigned)v, 63);
    unsigned rhi = (unsigned)__builtin_amdgcn_readlane((int)(unsigned)(v >> 32), 63);
    return ((unsigned long long)rhi << 32) | rlo;
}

// ---------- FPS v5 (proven, standalone again): 4 waves, one barrier/iter ----------
__global__ __launch_bounds__(256, 1) void fps_kernel_v5(const float* __restrict__ pts,
                                                        f32x4* __restrict__ center4) {
    int b = blockIdx.x;
    const float* P = pts + (size_t)b * NPTS * 3;
    int tid = threadIdx.x;
    int lane = tid & 63, wave = tid >> 6;
    __shared__ __align__(16) float Pl[NPTS * 3];
    __shared__ __align__(16) float slot[2][4][8];   // [parity][wave]{klo,khi,x,y,z}
#pragma unroll
    for (int i = 0; i < 6; ++i) {    // 1536 float4 = 24 KB, coalesced
        int v4 = tid + i * 256;
        ((f32x4*)Pl)[v4] = ((const f32x4*)P)[v4];
    }
    __syncthreads();
    float px[8], py[8], pz[8], mind[8];
#pragma unroll
    for (int m = 0; m < 8; ++m) {
        int j = tid + (m << 8);
        px[m] = Pl[j * 3 + 0];
        py[m] = Pl[j * 3 + 1];
        pz[m] = Pl[j * 3 + 2];
        mind[m] = 1e10f;
    }
    float cx = Pl[0], cy = Pl[1], cz = Pl[2];   // far = 0
    f32x4* C4 = center4 + (size_t)b * NG;
#pragma unroll 1
    for (int g = 0; g < NG; ++g) {
        if (tid == 0) C4[g] = (f32x4){cx, cy, cz, cx * cx + cy * cy + cz * cz};
        if (g == NG - 1) break;      // uniform: all threads exit together
        float best0 = -1.f, best1 = -1.f;
        int bm0 = 0, bm1 = 1;
#pragma unroll
        for (int m = 0; m < 8; m += 2) {   // 2 independent dep chains
            float dx0 = px[m] - cx, dy0 = py[m] - cy, dz0 = pz[m] - cz;
            float d0 = dx0 * dx0 + dy0 * dy0 + dz0 * dz0;
            float md0 = fminf(mind[m], d0);
            mind[m] = md0;
            if (md0 > best0) { best0 = md0; bm0 = m; }        // strict >: min m on tie
            float dx1 = px[m + 1] - cx, dy1 = py[m + 1] - cy, dz1 = pz[m + 1] - cz;
            float d1 = dx1 * dx1 + dy1 * dy1 + dz1 * dz1;
            float md1 = fminf(mind[m + 1], d1);
            mind[m + 1] = md1;
            if (md1 > best1) { best1 = md1; bm1 = m + 1; }
        }
        bool t = (best1 > best0) || (best1 == best0 && bm1 < bm0);
        float bv = t ? best1 : best0;
        int bi = t ? bm1 : bm0;
        unsigned j = (unsigned)(tid + (bi << 8));   // global point index
        unsigned long long key =
            ((unsigned long long)__float_as_uint(bv) << 32) | (unsigned)(~j);
        key = wave_max_u64(key);                    // broadcast to all lanes
        unsigned bj = ~(unsigned)key;
        int par = g & 1;
        if (lane < 3) slot[par][wave][2 + lane] = Pl[bj * 3 + lane];  // prefetch coords
        if (lane == 0) {
            slot[par][wave][0] = __uint_as_float((unsigned)key);
            slot[par][wave][1] = __uint_as_float((unsigned)(key >> 32));
        }
        __syncthreads();
        unsigned long long kb = 0ull;
        float nx = 0.f, ny = 0.f, nz = 0.f;
#pragma unroll
        for (int w = 0; w < 4; ++w) {
            f32x4 v = *(const f32x4*)&slot[par][w][0];   // klo,khi,x,y
            float vz = slot[par][w][4];
            unsigned long long kk =
                ((unsigned long long)__float_as_uint(v[1]) << 32) | __float_as_uint(v[0]);
            bool tw = kk > kb;
            kb = tw ? kk : kb;
            nx = tw ? v[2] : nx;
            ny = tw ? v[3] : ny;
            nz = tw ? vz : nz;
        }
        cx = nx; cy = ny; cz = nz;
    }
}

// ---------- fused weight cvt + pts4 pack + key/accum zero-init (proven) ----------
__global__ void cvt_all_kernel(const float* __restrict__ W2, const float* __restrict__ W3,
                               const float* __restrict__ W4, const float* __restrict__ pts,
                               f16* __restrict__ W2h, f16* __restrict__ W3h,
                               f16* __restrict__ W4h, f32x4* __restrict__ pts4,
                               unsigned* __restrict__ keybase, int zero_words) {
    int t = blockIdx.x * 256 + threadIdx.x;
    if (t < 32768) {                       // W2h: 256x128, ld 128, off 0
        int n = t >> 7, k = t & 127;
        W2h[t] = (f16)W2[(size_t)n * 128 + k];
    } else if (t < 163840) {               // W3h: 512x256, ld 512, off 256
        int u = t - 32768;
        int n = u >> 8, k = u & 255;
        W3h[u] = (f16)W3[(size_t)n * 512 + 256 + k];
    } else if (t < 688128) {               // W4h: 1024x512, ld 512, off 0
        int u = t - 163840;
        int n = u >> 9, k = u & 511;
        W4h[u] = (f16)W4[(size_t)n * 512 + k];
    } else if (t < 720896) {               // pts4 pack (BSZ*NPTS = 32768)
        int u = t - 688128;
        float x = pts[(size_t)u * 3 + 0], y = pts[(size_t)u * 3 + 1],
              z = pts[(size_t)u * 3 + 2];
        pts4[u] = (f32x4){x, y, z, x * x + y * y + z * z};
    } else if (t < 720896 + zero_words) {  // zero atomic key buffers + accum + ticket
        keybase[t - 720896] = 0u;
    }
}

// ---------- KNN core v9 (unchanged): lane r holds r-th NN index ----------
__device__ __forceinline__ int knn_query_core(f32x4 q, const f32x4* __restrict__ db4,
                                              int k, int lane) {
    const unsigned KINF = 0xFFFFFFFFu;
    float m2x = -2.f * q[0], m2y = -2.f * q[1], m2z = -2.f * q[2], qq = q[3];
    unsigned key[32];
    unsigned c0 = KINF, c1 = KINF, c2 = KINF, c3 = KINF;
#pragma unroll
    for (int m = 0; m < 32; ++m) {
        int j = lane + (m << 6);
        f32x4 b = db4[j];
        float t = fmaf(m2x, b[0], b[3]);
        t = fmaf(m2y, b[1], t);
        t = fmaf(m2z, b[2], t);
        float dv = qq + t;
        unsigned qd = (unsigned)fminf(fmaxf(dv, 0.f) * 8192.0f, 2097151.f);
        unsigned kk = (qd << 11) | (unsigned)j;
        key[m] = kk;
        if (kk < c3) {
            if (kk < c2) {
                c3 = c2;
                if (kk < c1) {
                    c2 = c1;
                    if (kk < c0) { c1 = c0; c0 = kk; } else c1 = kk;
                } else c2 = kk;
            } else c3 = kk;
        }
    }
    unsigned hw = c3;
    int ncached = 4;
    int mywin = 0;
    for (int r = 0; r < k; ++r) {
        bool need = (c0 == KINF) && (ncached < 32);
        if (__any(need)) {
            unsigned best = KINF;
#pragma unroll
            for (int m = 0; m < 32; ++m) {
                unsigned v = key[m];
                best = (v > hw && v < best) ? v : best;
            }
            if (need) {
                c0 = best;
                hw = best;
                ncached = (best == KINF) ? 32 : ncached + 1;
            }
        }
        unsigned g = wave_min_u32(c0);
        int idx = (int)(g & 0x7FFu);
        if (lane == r) mywin = idx;
        if (((unsigned)idx & 63u) == (unsigned)lane) {   // owner pops its c0 (== g)
            c0 = c1; c1 = c2; c2 = c3; c3 = KINF;
        }
    }
    return mywin;
}

// ---------- group KNN + direct gather (unchanged) ----------
__global__ void knn_group_gather_kernel(const f32x4* __restrict__ center4,
                                        const f32x4* __restrict__ pts4,
                                        f32x4* __restrict__ r0p4,
                                        f32x4* __restrict__ r1p4) {
    int wave = threadIdx.x >> 6, lane = threadIdx.x & 63;
    int qidx = blockIdx.x * 4 + wave;          // [0, BSZ*96)
    int b = qidx / 96, qi = qidx - b * 96;
    const f32x4* db4 = pts4 + (size_t)b * NPTS;
    int win = knn_query_core(center4[(size_t)b * NG + qi], db4, GS, lane);
    if (lane < GS) {
        f32x4 p = db4[win];
        if (qi < 64) r0p4[(size_t)b * 2048 + qi * GS + lane] = p;
        else         r1p4[(size_t)b * 1024 + (qi - 64) * GS + lane] = p;
    }
}

// ---------- post-decoder KNN + direct gather + self-KNN (unchanged) ----------
__global__ void knn_post_kernel(const f32x4* __restrict__ center4,
                                const f32x4* __restrict__ pred4,
                                f32x4* __restrict__ gap4, f32x4* __restrict__ gbp4,
                                f32x4* __restrict__ gathc4, int* __restrict__ knn32) {
    int wave = threadIdx.x >> 6, lane = threadIdx.x & 63;
    if (blockIdx.x < 512) {
        int qidx = blockIdx.x * 4 + wave;        // 2048 = BSZ*128 exact
        int b = qidx >> 7, qi = qidx & 127;
        const f32x4* db4 = pred4 + (size_t)b * NPTS;
        int k = (qi < 96) ? NBRK : GS;           // wave-uniform
        int win = knn_query_core(center4[(size_t)b * NG + qi], db4, k, lane);
        if (lane < k) {
            f32x4 p = db4[win];
            if (qi < 64)      gap4[(size_t)b * 2432 + qi * NBRK + lane] = p;
            else if (qi < 96) gbp4[(size_t)b * 1216 + (qi - 64) * NBRK + lane] = p;
            else              gathc4[(size_t)b * 1024 + (qi - 96) * GS + lane] = p;
        }
    } else {
        int qidx = (blockIdx.x - 512) * 4 + wave;   // 32768 = BSZ*2048 exact
        int b = qidx >> 11, qi = qidx & 2047;
        const f32x4* db4 = pred4 + (size_t)b * NPTS;
        int win = knn_query_core(db4[qi], db4, GS, lane);
        if (lane < GS) knn32[(size_t)qidx * GS + lane] = win;
    }
}

// ---------- layer1 (unchanged) ----------
__global__ void layer1_kernel(const f32x4* __restrict__ X4, const float* __restrict__ W1,
                              const float* __restrict__ b1, const float* __restrict__ g1,
                              const float* __restrict__ be1, const float* __restrict__ m1,
                              const float* __restrict__ v1, f16* __restrict__ H1, int M) {
    __shared__ float w[384], bb[128], sg[128], sb[128], sm[128], sv[128];
    for (int i = threadIdx.x; i < 384; i += 256) w[i] = W1[i];
    if (threadIdx.x < 128) {
        int c = threadIdx.x;
        bb[c] = b1[c]; sg[c] = g1[c]; sb[c] = be1[c]; sm[c] = m1[c]; sv[c] = v1[c];
    }
    __syncthreads();
    int t = blockIdx.x * 256 + threadIdx.x;
    if (t >= M * 16) return;
    int row = t >> 4, cg = (t & 15) * 8;
    f32x4 xv = X4[row];
    float x0 = xv[0], x1 = xv[1], x2 = xv[2];
    f16x8 outv;
#pragma unroll
    for (int j = 0; j < 8; ++j) {
        int c = cg + j;
        float tv = x0 * w[c * 3] + x1 * w[c * 3 + 1] + x2 * w[c * 3 + 2] + bb[c];
        float vv = (tv - sm[c]) * rsqrtf(sv[c] + 1e-5f) * sg[c] + sb[c];
        outv[j] = (f16)fmaxf(vv, 0.f);
    }
    *(f16x8*)&H1[(size_t)row * 128 + cg] = outv;
}

// ---------- MFMA GEMM v3: parity double-buffered LDS -> ONE barrier per k-iter ----------
// R4 counters: ~56% stall with 2 barriers/iter (MfmaUtil 15%, VALUBusy 29%).
// Parity buffers make the write->read hazard one-sided: reads of buf[p] at iter i
// complete before that thread's MFMAs (compiler lgkmcnt); every thread passes
// barrier(i+1) after that; writes to buf[p] resume at iter i+2 > barrier(i+1).
// LDS 20.5->41 KB caps 3 blocks/CU; measured residency was ~2.3 -> no occupancy loss.
__global__ __launch_bounds__(256) void mfma_gemm_kernel(
        const f16* __restrict__ A, const f16* __restrict__ W, int K, int N,
        const float* __restrict__ bias, const float* __restrict__ bias2d,
        const float* __restrict__ bng, const float* __restrict__ bnb,
        const float* __restrict__ bnm, const float* __restrict__ bnv,
        f16* __restrict__ Cout, unsigned* __restrict__ maxkey,
        int rows_per_batch, int relu) {
    __shared__ f16 Als[2][128 * 40];
    __shared__ f16 Bls[2][128 * 40];
    int tid = threadIdx.x;
    int lane = tid & 63;
    int wave = tid >> 6;
    int wm = wave & 1, wn = wave >> 1;
    int c16 = lane & 15, quad = lane >> 4;
    int gx = gridDim.x;
    int nwg = gx * gridDim.y;
    int lin = blockIdx.y * gx + blockIdx.x;
    int qc = nwg >> 3, rc = nwg & 7;
    int xcd = lin & 7, pos = lin >> 3;
    int nlin = (xcd < rc ? xcd * (qc + 1) : rc * (qc + 1) + (xcd - rc) * qc) + pos;
    int row0 = (nlin / gx) * 128, col0 = (nlin % gx) * 128;
    int sr = tid >> 2;
    int skc = (tid & 3) * 8;

    f32x4 acc[4][4];
#pragma unroll
    for (int i = 0; i < 4; ++i)
#pragma unroll
        for (int j = 0; j < 4; ++j) acc[i][j] = (f32x4){0.f, 0.f, 0.f, 0.f};

    const f16* Ab = A + (size_t)(row0 + sr) * K + skc;
    const f16* Ab2 = A + (size_t)(row0 + sr + 64) * K + skc;
    const f16* Wb = W + (size_t)(col0 + sr) * K + skc;
    const f16* Wb2 = W + (size_t)(col0 + sr + 64) * K + skc;

    f16x8 pa0 = *(const f16x8*)Ab;
    f16x8 pa1 = *(const f16x8*)Ab2;
    f16x8 pb0 = *(const f16x8*)Wb;
    f16x8 pb1 = *(const f16x8*)Wb2;

    int p = 0;
    for (int k0 = 0; k0 < K; k0 += 32, p ^= 1) {
        *(f16x8*)&Als[p][sr * 40 + skc] = pa0;
        *(f16x8*)&Als[p][(sr + 64) * 40 + skc] = pa1;
        *(f16x8*)&Bls[p][sr * 40 + skc] = pb0;
        *(f16x8*)&Bls[p][(sr + 64) * 40 + skc] = pb1;
        __syncthreads();
        if (k0 + 32 < K) {            // prefetch next tile; consumed at next ds_write
            int kn = k0 + 32;
            pa0 = *(const f16x8*)(Ab + kn);
            pa1 = *(const f16x8*)(Ab2 + kn);
            pb0 = *(const f16x8*)(Wb + kn);
            pb1 = *(const f16x8*)(Wb2 + kn);
        }
        f16x8 af[4], bf[4];
#pragma unroll
        for (int s = 0; s < 4; ++s) {
            af[s] = *(const f16x8*)&Als[p][(wm * 64 + s * 16 + c16) * 40 + quad * 8];
            bf[s] = *(const f16x8*)&Bls[p][(wn * 64 + s * 16 + c16) * 40 + quad * 8];
        }
#pragma unroll
        for (int ms = 0; ms < 4; ++ms)
#pragma unroll
            for (int ns = 0; ns < 4; ++ns)
                acc[ms][ns] = __builtin_amdgcn_mfma_f32_16x16x32_f16(af[ms], bf[ns],
                                                                     acc[ms][ns], 0, 0, 0);
        // no second barrier: parity buffer + barrier(i+1) covers the reuse hazard
    }

    int b = row0 / rows_per_batch;
#pragma unroll
    for (int ns = 0; ns < 4; ++ns) {
        int col = col0 + wn * 64 + ns * 16 + c16;
        float bv = bias ? bias[col] : 0.f;
        float b2v = bias2d ? bias2d[(size_t)b * N + col] : 0.f;
        float mx = -3e38f;
#pragma unroll
        for (int ms = 0; ms < 4; ++ms) {
#pragma unroll
            for (int j = 0; j < 4; ++j) {
                float v = acc[ms][ns][j] + bv + b2v;
                if (bng) v = (v - bnm[col]) * rsqrtf(bnv[col] + 1e-5f) * bng[col] + bnb[col];
                if (relu) v = fmaxf(v, 0.f);
                if (Cout)
                    Cout[(size_t)(row0 + wm * 64 + ms * 16 + quad * 4 + j) * N + col] = (f16)v;
                mx = fmaxf(mx, v);
            }
        }
        if (maxkey) {
            mx = fmaxf(mx, __shfl_xor(mx, 16, 64));
            mx = fmaxf(mx, __shfl_xor(mx, 32, 64));
            if (quad == 0) atomicMax(&maxkey[(size_t)b * N + col], fkey(mx));
        }
    }
}

// ---------- skinny GEMM v3 (unchanged) ----------
__global__ void skinny_v2_kernel(const float* __restrict__ A, const float* __restrict__ W,
                                 int ldw, int woff, const float* __restrict__ bias,
                                 float* __restrict__ C, int K, int N, int relu, int akey) {
    int wave = threadIdx.x >> 6, lane = threadIdx.x & 63;
    int col = blockIdx.x * 4 + wave;
    if (col >= N) return;
    const float* w = W + (size_t)col * ldw + woff;
    float acc[16];
#pragma unroll
    for (int m = 0; m < 16; ++m) acc[m] = 0.f;
    for (int k0 = 0; k0 < K; k0 += 256) {
        f32x4 wv = *(const f32x4*)(w + k0 + lane * 4);
#pragma unroll
        for (int m = 0; m < 16; ++m) {
            f32x4 av = *(const f32x4*)(A + (size_t)m * K + k0 + lane * 4);
            if (akey) {
#pragma unroll
                for (int u = 0; u < 4; ++u) av[u] = fkey_inv(__float_as_uint(av[u]));
            }
            acc[m] += av[0] * wv[0] + av[1] * wv[1] + av[2] * wv[2] + av[3] * wv[3];
        }
    }
#pragma unroll
    for (int m = 0; m < 16; ++m)
#pragma unroll
        for (int s = 1; s < 64; s <<= 1) acc[m] += __shfl_xor(acc[m], s, 64);
    if (lane == 0) {
        float bv = bias[col];
#pragma unroll
        for (int m = 0; m < 16; ++m) {
            float v = acc[m] + bv;
            if (relu) v = fmaxf(v, 0.f);
            C[(size_t)m * N + col] = v;
        }
    }
}

// ---------- D4 skinny variant (unchanged): packed pred4 out ----------
__global__ void skinny_pred3_kernel(const float* __restrict__ A,
                                    const float* __restrict__ W,
                                    const float* __restrict__ bias,
                                    f32x4* __restrict__ pred4) {
    int wave = threadIdx.x >> 6, lane = threadIdx.x & 63;
    int p = blockIdx.x * 4 + wave;           // [0, 2048)
    const float* w0 = W + (size_t)(3 * p + 0) * 2048;
    const float* w1 = W + (size_t)(3 * p + 1) * 2048;
    const float* w2 = W + (size_t)(3 * p + 2) * 2048;
    float ax[16], ay[16], az[16];
#pragma unroll
    for (int m = 0; m < 16; ++m) { ax[m] = 0.f; ay[m] = 0.f; az[m] = 0.f; }
    for (int k0 = 0; k0 < 2048; k0 += 256) {
        f32x4 wx = *(const f32x4*)(w0 + k0 + lane * 4);
        f32x4 wy = *(const f32x4*)(w1 + k0 + lane * 4);
        f32x4 wz = *(const f32x4*)(w2 + k0 + lane * 4);
#pragma unroll
        for (int m = 0; m < 16; ++m) {
            f32x4 av = *(const f32x4*)(A + (size_t)m * 2048 + k0 + lane * 4);
            ax[m] += av[0] * wx[0] + av[1] * wx[1] + av[2] * wx[2] + av[3] * wx[3];
            ay[m] += av[0] * wy[0] + av[1] * wy[1] + av[2] * wy[2] + av[3] * wy[3];
            az[m] += av[0] * wz[0] + av[1] * wz[1] + av[2] * wz[2] + av[3] * wz[3];
        }
    }
#pragma unroll
    for (int m = 0; m < 16; ++m)
#pragma unroll
        for (int s = 1; s < 64; s <<= 1) {
            ax[m] += __shfl_xor(ax[m], s, 64);
            ay[m] += __shfl_xor(ay[m], s, 64);
            az[m] += __shfl_xor(az[m], s, 64);
        }
    if (lane == 0) {
        float bx = bias[3 * p + 0], by = bias[3 * p + 1], bz = bias[3 * p + 2];
#pragma unroll
        for (int m = 0; m < 16; ++m) {
            float x = ax[m] + bx, y = ay[m] + by, z = az[m] + bz;
            pred4[(size_t)m * 2048 + p] = (f32x4){x, y, z, x * x + y * y + z * z};
        }
    }
}

// ---------- 3x3 symmetric smallest eigenvector (double, analytic) ----------
__device__ void smallest_evec(double cxx, double cxy, double cxz,
                              double cyy, double cyz, double czz, double ev[3]) {
    double p1 = cxy * cxy + cxz * cxz + cyz * cyz;
    double q = (cxx + cyy + czz) / 3.0;
    double p2 = (cxx - q) * (cxx - q) + (cyy - q) * (cyy - q) + (czz - q) * (czz - q) + 2.0 * p1;
    double lam = q;
    if (p2 > 0.0) {
        double p = sqrt(p2 / 6.0);
        double b00 = (cxx - q) / p, b11 = (cyy - q) / p, b22 = (czz - q) / p;
        double b01 = cxy / p, b02 = cxz / p, b12 = cyz / p;
        double detB = b00 * (b11 * b22 - b12 * b12) - b01 * (b01 * b22 - b12 * b02)
                    + b02 * (b01 * b12 - b11 * b02);
        double r = detB * 0.5;
        r = r < -1.0 ? -1.0 : (r > 1.0 ? 1.0 : r);
        double phi = acos(r) / 3.0;
        lam = q + 2.0 * p * cos(phi + 2.0943951023931953);
    }
    double r0x = cxx - lam, r0y = cxy, r0z = cxz;
    double r1x = cxy, r1y = cyy - lam, r1z = cyz;
    double r2x = cxz, r2y = cyz, r2z = czz - lam;
    double c0x = r0y * r1z - r0z * r1y, c0y = r0z * r1x - r0x * r1z, c0z = r0x * r1y - r0y * r1x;
    double c1x = r0y * r2z - r0z * r2y, c1y = r0z * r2x - r0x * r2z, c1z = r0x * r2y - r0y * r2x;
    double c2x = r1y * r2z - r1z * r2y, c2y = r1z * r2x - r1x * r2z, c2z = r1x * r2y - r1y * r2x;
    double n0 = c0x * c0x + c0y * c0y + c0z * c0z;
    double n1 = c1x * c1x + c1y * c1y + c1z * c1z;
    double n2 = c2x * c2x + c2y * c2y + c2z * c2z;
    double bx = c0x, by = c0y, bz = c0z, bn = n0;
    if (n1 > bn) { bx = c1x; by = c1y; bz = c1z; bn = n1; }
    if (n2 > bn) { bx = c2x; by = c2y; bz = c2z; bn = n2; }
    if (bn < 1e-280) { ev[0] = 1.0; ev[1] = 0.0; ev[2] = 0.0; return; }
    double inv = 1.0 / sqrt(bn);
    ev[0] = bx * inv; ev[1] = by * inv; ev[2] = bz * inv;
}

// ---------- fused chamfer + normals: both depend only on knn_post outputs ----------
// blocks [0,432): chamfer x4 (LDS-broadcast inner loop, unchanged math);
// blocks [432,560): normals, 256 threads/block over BSZ*NPTS points.
__global__ __launch_bounds__(256) void chamfer_normals_kernel(
        const f32x4* __restrict__ r0p4, const f32x4* __restrict__ gap4,
        const f32x4* __restrict__ r1p4, const f32x4* __restrict__ gbp4,
        float* __restrict__ accum, const f32x4* __restrict__ pred4,
        const int* __restrict__ knn32, float* __restrict__ nrm) {
    __shared__ __align__(16) float Bl[2432 * 4];   // 38.9 KB (chamfer blocks only)
    int blk = blockIdx.x;
    if (blk >= 432) {
        // ---- normals path ----
        int t = (blk - 432) * 256 + threadIdx.x;   // BSZ*NPTS = 32768 exact
        int b = t >> 11, i = t & 2047;
        const f32x4* P4 = pred4 + (size_t)b * NPTS;
        const int* id = knn32 + (size_t)t * 32;
        double sx = 0, sy = 0, sz = 0;
        double sxx = 0, sxy = 0, sxz = 0, syy = 0, syz = 0, szz = 0;
#pragma unroll
        for (int k0 = 0; k0 < 32; k0 += 4) {
            int4 jj = *(const int4*)&id[k0];
#pragma unroll
            for (int u = 0; u < 4; ++u) {
                int j = (u == 0) ? jj.x : (u == 1) ? jj.y : (u == 2) ? jj.z : jj.w;
                f32x4 p = P4[j];
                double x = (double)p[0], y = (double)p[1], z = (double)p[2];
                sx += x; sy += y; sz += z;
                sxx += x * x; sxy += x * y; sxz += x * z;
                syy += y * y; syz += y * z; szz += z * z;
            }
        }
        double mx = sx * (1.0 / 32.0), my = sy * (1.0 / 32.0), mz = sz * (1.0 / 32.0);
        double cxx = sxx * (1.0 / 32.0) - mx * mx;
        double cxy = sxy * (1.0 / 32.0) - mx * my;
        double cxz = sxz * (1.0 / 32.0) - mx * mz;
        double cyy = syy * (1.0 / 32.0) - my * my;
        double cyz = syz * (1.0 / 32.0) - my * mz;
        double czz = szz * (1.0 / 32.0) - mz * mz;
        double ev[3];
        smallest_evec(cxx, cxy, cxz, cyy, cyz, czz, ev);
        f32x4 q = P4[i];
        double proj = (sx - 32.0 * (double)q[0]) * ev[0]
                    + (sy - 32.0 * (double)q[1]) * ev[1]
                    + (sz - 32.0 * (double)q[2]) * ev[2];
        double s = (proj >= 0.0) ? 1.0 : -1.0;
        nrm[(size_t)t * 3 + 0] = (float)(ev[0] * s);
        nrm[(size_t)t * 3 + 1] = (float)(ev[1] * s);
        nrm[(size_t)t * 3 + 2] = (float)(ev[2] * s);
        return;
    }
    // ---- chamfer path ----
    const f32x4 *A4, *B4; int na, nb, base, bpb; float* slot;
    if (blk < 128)      { A4 = r0p4; na = 2048; B4 = gap4; nb = 2432; slot = accum + 0; base = 0;   bpb = 8; }
    else if (blk < 288) { A4 = gap4; na = 2432; B4 = r0p4; nb = 2048; slot = accum + 1; base = 128; bpb = 10; }
    else if (blk < 352) { A4 = r1p4; na = 1024; B4 = gbp4; nb = 1216; slot = accum + 2; base = 288; bpb = 4; }
    else                { A4 = gbp4; na = 1216; B4 = r1p4; nb = 1024; slot = accum + 3; base = 352; bpb = 5; }
    int rel = blk - base;
    int b = rel / bpb, chunk = rel - b * bpb;
    for (int i = threadIdx.x; i < nb; i += 256)
        ((f32x4*)Bl)[i] = B4[(size_t)b * nb + i];
    __syncthreads();
    int aidx = chunk * 256 + threadIdx.x;
    float val = 0.f;
    if (aidx < na) {
        f32x4 a = A4[(size_t)b * na + aidx];
        float m2x = -2.f * a[0], m2y = -2.f * a[1], m2z = -2.f * a[2];
        float m0 = 3e38f, m1 = 3e38f, m2 = 3e38f, m3 = 3e38f;   // 4 indep chains
        for (int j = 0; j < nb; j += 4) {                       // nb % 4 == 0 always
            f32x4 b0 = ((const f32x4*)Bl)[j + 0];
            f32x4 b1 = ((const f32x4*)Bl)[j + 1];
            f32x4 b2 = ((const f32x4*)Bl)[j + 2];
            f32x4 b3 = ((const f32x4*)Bl)[j + 3];
            float t0 = fmaf(m2z, b0[2], fmaf(m2y, b0[1], fmaf(m2x, b0[0], b0[3])));
            float t1 = fmaf(m2z, b1[2], fmaf(m2y, b1[1], fmaf(m2x, b1[0], b1[3])));
            float t2 = fmaf(m2z, b2[2], fmaf(m2y, b2[1], fmaf(m2x, b2[0], b2[3])));
            float t3 = fmaf(m2z, b3[2], fmaf(m2y, b3[1], fmaf(m2x, b3[0], b3[3])));
            m0 = fminf(m0, t0); m1 = fminf(m1, t1);
            m2 = fminf(m2, t2); m3 = fminf(m3, t3);
        }
        float m = fminf(fminf(m0, m1), fminf(m2, m3));
        val = sqrtf(fmaxf(a[3] + m, 1e-12f));
    }
    __shared__ float sdata[256];
    sdata[threadIdx.x] = val;
    __syncthreads();
    for (int s = 128; s > 0; s >>= 1) {
        if (threadIdx.x < s) sdata[threadIdx.x] += sdata[threadIdx.x + s];
        __syncthreads();
    }
    if (threadIdx.x == 0) atomicAdd(slot, sdata[0]);
}

// ---------- fused loss tail + finalize (completion-ticket, unchanged) ----------
__global__ void loss_tail_kernel(const float* __restrict__ nrm,
                                 const int* __restrict__ knn32,
                                 const unsigned* __restrict__ k1,
                                 const unsigned* __restrict__ k2,
                                 float* __restrict__ accum,
                                 float* __restrict__ out) {
    float val = 0.f;
    float* slot;
    if (blockIdx.x < 128) {
        slot = accum + 5;
        int t = blockIdx.x * 256 + threadIdx.x;      // BSZ*2048 = 32768 exact
        int b = t >> 11;
        const float* NB = nrm + (size_t)b * NPTS * 3;
        const int* id = knn32 + (size_t)t * 32;
        int j0 = id[0];
        float ax = NB[j0 * 3 + 0], ay = NB[j0 * 3 + 1], az = NB[j0 * 3 + 2];
        float an = fmaxf(sqrtf(ax * ax + ay * ay + az * az), 1e-6f);
        float x[8]; float s = 0.f;
        for (int k = 0; k < 8; ++k) {
            int j = id[k];
            float bx = NB[j * 3 + 0], by = NB[j * 3 + 1], bz = NB[j * 3 + 2];
            float bn_ = fmaxf(sqrtf(bx * bx + by * by + bz * bz), 1e-6f);
            float c = (ax * bx + ay * by + az * bz) / (an * bn_);
            x[k] = 1.f - c; s += x[k];
        }
        float mean = s / 8.f;
        float var = 0.f;
        for (int k = 0; k < 8; ++k) { float d = x[k] - mean; var += d * d; }
        val = sqrtf(var / 7.f);
    } else {
        slot = accum + 4;
        int t = (blockIdx.x - 128) * 256 + threadIdx.x;   // BSZ*1024 = 16384 exact
        float d = fkey_inv(k1[t]) - fkey_inv(k2[t]);
        float ad = fabsf(d);
        val = (ad < 1.f) ? (0.5f * d * d) : (ad - 0.5f);
    }
    __shared__ float sdata[256];
    sdata[threadIdx.x] = val;
    __syncthreads();
    for (int s2 = 128; s2 > 0; s2 >>= 1) {
        if (threadIdx.x < s2) sdata[threadIdx.x] += sdata[threadIdx.x + s2];
        __syncthreads();
    }
    if (threadIdx.x == 0) {
        atomicAdd(slot, sdata[0]);
        __threadfence();
        unsigned tk = atomicAdd((unsigned*)(accum + 6), 1u);
        if (tk == 191u) {                 // last block: all adds visible
            float a0 = atomicAdd(&accum[0], 0.f);
            float a1 = atomicAdd(&accum[1], 0.f);
            float a2 = atomicAdd(&accum[2], 0.f);
            float a3 = atomicAdd(&accum[3], 0.f);
            float a4 = atomicAdd(&accum[4], 0.f);
            float a5 = atomicAdd(&accum[5], 0.f);
            float l_recon = 0.5f * (a0 / (16.f * 2048.f) + a1 / (16.f * 2432.f));
            float l_match = 0.5f * (a2 / (16.f * 1024.f) + a3 / (16.f * 1216.f));
            float l_latent = a4 / (16.f * 1024.f);
            float l_man = 0.1f * (a5 / (16.f * 2048.f));
            out[0] = l_recon + l_match + l_latent + l_man;
            out[1] = l_recon;
            out[2] = l_match;
            out[3] = l_latent;
            out[4] = l_man;
        }
    }
}

// ================= host =================
extern "C" void kernel_launch(void* const* d_in, const int* in_sizes, int n_in,
                              void* d_out, int out_size, void* d_ws, size_t ws_size,
                              hipStream_t stream) {
    (void)in_sizes; (void)n_in; (void)out_size; (void)ws_size;
    const float* pts = (const float*)d_in[0];
    const float* W1 = (const float*)d_in[1];
    const float* b1 = (const float*)d_in[2];
    const float* g1 = (const float*)d_in[3];
    const float* be1 = (const float*)d_in[4];
    const float* m1 = (const float*)d_in[5];
    const float* v1 = (const float*)d_in[6];
    const float* W2 = (const float*)d_in[7];
    const float* b2 = (const float*)d_in[8];
    const float* W3 = (const float*)d_in[9];
    const float* b3 = (const float*)d_in[10];
    const float* g2 = (const float*)d_in[11];
    const float* be2 = (const float*)d_in[12];
    const float* m2 = (const float*)d_in[13];
    const float* v2 = (const float*)d_in[14];
    const float* W4 = (const float*)d_in[15];
    const float* b4 = (const float*)d_in[16];
    const float* D1W = (const float*)d_in[17];
    const float* D1b = (const float*)d_in[18];
    const float* D2W = (const float*)d_in[19];
    const float* D2b = (const float*)d_in[20];
    const float* D3W = (const float*)d_in[21];
    const float* D3b = (const float*)d_in[22];
    const float* D4W = (const float*)d_in[23];
    const float* D4b = (const float*)d_in[24];

    char* ws = (char*)d_ws;
    size_t off = 0;
    auto alloc = [&](size_t bytes) -> void* {
        void* p = ws + off;
        off += (bytes + 255) & ~(size_t)255;
        return p;
    };
    f32x4* center4  = (f32x4*)alloc((size_t)BSZ * NG * 16);
    f32x4* pts4     = (f32x4*)alloc((size_t)BSZ * NPTS * 16);
    f32x4* pred4    = (f32x4*)alloc((size_t)BSZ * NPTS * 16);
    f32x4* r0p4     = (f32x4*)alloc((size_t)BSZ * 2048 * 16);
    f32x4* r1p4     = (f32x4*)alloc((size_t)BSZ * 1024 * 16);
    f16*   W2h      = (f16*)  alloc((size_t)256 * 128 * 2);
    f16*   W3h      = (f16*)  alloc((size_t)512 * 256 * 2);
    f16*   W4h      = (f16*)  alloc((size_t)1024 * 512 * 2);
    f16*   H1h      = (f16*)  alloc((size_t)BSZ * 2048 * 128 * 2);
    f16*   H2h      = (f16*)  alloc((size_t)BSZ * 2048 * 256 * 2);
    f16*   H3h      = (f16*)  alloc((size_t)BSZ * 2048 * 512 * 2);
    // contiguous key region + accum + ticket: zero-inited by cvt_all
    const int kZeroWords = BSZ * 2560 + 16;
    unsigned* keybase = (unsigned*)alloc(((size_t)BSZ * 2560 + 64) * 4);
    unsigned* gmaxkey1 = keybase;
    unsigned* gmaxkey2 = keybase + (size_t)BSZ * 256;
    unsigned* featkey1 = keybase + (size_t)BSZ * 512;
    unsigned* featkey2 = keybase + (size_t)BSZ * 512 + (size_t)BSZ * 1024;
    float* accum = (float*)(keybase + (size_t)BSZ * 2560);
    float* gpart    = (float*)alloc((size_t)BSZ * 512 * 4);
    float* dh1      = (float*)alloc((size_t)BSZ * 2048 * 4);
    float* dh2      = (float*)alloc((size_t)BSZ * 2048 * 4);
    float* dh3      = (float*)alloc((size_t)BSZ * 2048 * 4);
    f32x4* gap4     = (f32x4*)alloc((size_t)BSZ * 2432 * 16);
    f32x4* gbp4     = (f32x4*)alloc((size_t)BSZ * 1216 * 16);
    f32x4* gathc4   = (f32x4*)alloc((size_t)BSZ * 1024 * 16);
    int*   knn32    = (int*)  alloc((size_t)BSZ * 2048 * 32 * 4);
    float* nrmbuf   = (float*)alloc((size_t)BSZ * 2048 * 3 * 4);

    // 1: weights cvt + pts4 pack + zero keys/accum/ticket
    cvt_all_kernel<<<(720896 + kZeroWords + 255) / 256, 256, 0, stream>>>(
        W2, W3, W4, pts, W2h, W3h, W4h, pts4, keybase, kZeroWords);

    // 2: FPS   3: group-KNN + direct gather
    fps_kernel_v5<<<BSZ, 256, 0, stream>>>(pts, center4);
    knn_group_gather_kernel<<<(BSZ * 96) / 4, 256, 0, stream>>>(center4, pts4,
                                                                r0p4, r1p4);

    // encoder: 5 dispatches
    auto enc = [&](const f32x4* X4, int n, unsigned* gkey, unsigned* fkeyout) {
        int M = BSZ * n;
        layer1_kernel<<<M / 16, 256, 0, stream>>>(X4, W1, b1, g1, be1, m1, v1, H1h, M);
        mfma_gemm_kernel<<<dim3(256 / 128, M / 128), 256, 0, stream>>>(
            H1h, W2h, 128, 256, b2, nullptr, nullptr, nullptr, nullptr, nullptr,
            H2h, gkey, n, 0);
        skinny_v2_kernel<<<(512 + 3) / 4, 256, 0, stream>>>(
            (const float*)gkey, W3, 512, 0, b3, gpart, 256, 512, 0, 1);
        mfma_gemm_kernel<<<dim3(512 / 128, M / 128), 256, 0, stream>>>(
            H2h, W3h, 256, 512, nullptr, gpart, g2, be2, m2, v2, H3h, nullptr, n, 1);
        mfma_gemm_kernel<<<dim3(1024 / 128, M / 128), 256, 0, stream>>>(
            H3h, W4h, 512, 1024, b4, nullptr, nullptr, nullptr, nullptr, nullptr,
            nullptr, fkeyout, n, 0);
    };

    // 4-8: enc1
    enc(r0p4, 2048, gmaxkey1, featkey1);

    // 9-12: decoder; D4 variant writes packed pred4
    skinny_v2_kernel<<<2048 / 4, 256, 0, stream>>>((const float*)featkey1, D1W, 1024, 0,
                                                   D1b, dh1, 1024, 2048, 1, 1);
    skinny_v2_kernel<<<2048 / 4, 256, 0, stream>>>(dh1, D2W, 2048, 0, D2b, dh2,
                                                   2048, 2048, 1, 0);
    skinny_v2_kernel<<<2048 / 4, 256, 0, stream>>>(dh2, D3W, 2048, 0, D3b, dh3,
                                                   2048, 2048, 1, 0);
    skinny_pred3_kernel<<<2048 / 4, 256, 0, stream>>>(dh3, D4W, D4b, pred4);

    // 13: all pred-database KNNs + direct gathers
    knn_post_kernel<<<512 + (BSZ * NPTS) / 4, 256, 0, stream>>>(center4, pred4, gap4,
                                                                gbp4, gathc4, knn32);
    // 14: chamfer x4 + normals fused (both depend only on knn_post)
    chamfer_normals_kernel<<<560, 256, 0, stream>>>(r0p4, gap4, r1p4, gbp4, accum,
                                                    pred4, knn32, nrmbuf);

    // 15-19: enc2
    enc(gathc4, 1024, gmaxkey2, featkey2);

    // 20: loss tail + fused finalize (ticket)
    loss_tail_kernel<<<192, 256, 0, stream>>>(nrmbuf, knn32, featkey1, featkey2,
                                              accum, (float*)d_out);
}